// Round 15
// baseline (420.769 us; speedup 1.0000x reference)
//
#include <hip/hip_runtime.h>
#include <cmath>

#define BB 2
#define SEQ 2048
#define DIM 1024
#define NH 16
#define DH 64
#define DEPTH 2
#define FFD 4096
#define CHK 64
#define NCHK (SEQ/CHK)      // 32
#define ROWS (BB*SEQ)       // 4096
#define QKP (3*DIM)         // fused qkv row pitch (3072)

typedef __bf16 bf16x8 __attribute__((ext_vector_type(8)));
typedef __bf16 bf16x4 __attribute__((ext_vector_type(4)));
typedef float  f32x4  __attribute__((ext_vector_type(4)));

#define AS1 __attribute__((address_space(1)))
#define AS3 __attribute__((address_space(3)))
#define FENCE() asm volatile("" ::: "memory")
#define LGKM0() asm volatile("s_waitcnt lgkmcnt(0)" ::: "memory")

template<int N> __device__ __forceinline__ void vmcnt_wait() {
    if constexpr (N == 0) asm volatile("s_waitcnt vmcnt(0)" ::: "memory");
    else if constexpr (N == 3) asm volatile("s_waitcnt vmcnt(3)" ::: "memory");
    else if constexpr (N == 4) asm volatile("s_waitcnt vmcnt(4)" ::: "memory");
    else if constexpr (N == 5) asm volatile("s_waitcnt vmcnt(5)" ::: "memory");
    else asm volatile("s_waitcnt vmcnt(6)" ::: "memory");
}

// tanh-form GELU: |err| < 1e-3 vs exact; invisible under bf16 rounding
__device__ __forceinline__ float gelu_fast(float x) {
    float x3 = x * x * x;
    float y = 1.5957691216057308f * (x + 0.044715f * x3);
    return x * __builtin_amdgcn_rcpf(1.0f + __expf(-y));
}

// swizzled halfword index into a row-pitch-64hw (128B) bf16 tile
__device__ __forceinline__ int swz128(int row, int col) {
    return row * 64 + (col ^ ((row & 7) << 3));
}

// T1: XCD-contiguous bijective block swizzle (m204) + width-4 column-group order
__device__ __forceinline__ void swz_tile(int bid, int NX, int NY, int& tx, int& ty) {
    int NB = NX * NY;
    int q = NB >> 3, r = NB & 7;
    int xcd = bid & 7, seq = bid >> 3;
    int start = (xcd < r) ? xcd * (q + 1) : r * (q + 1) + (xcd - r) * q;
    int wgid = start + seq;
    int g = 0, rem = wgid;
    int gw = (NX < 4) ? NX : 4;
    while (rem >= gw * NY) {
        rem -= gw * NY; g++;
        int left = NX - 4 * g;
        gw = left < 4 ? left : 4;
    }
    ty = rem / gw;
    tx = 4 * g + rem % gw;
}

// ---------------- LayerNorm (standalone; used only for layer-0 ln1) -------------
__global__ __launch_bounds__(256) void ln_kernel(
    const float* __restrict__ x, const float* __restrict__ g,
    const float* __restrict__ b, __bf16* __restrict__ out)
{
    int row = blockIdx.x;
    const float4* xr = (const float4*)(x + (size_t)row * DIM);
    int t = threadIdx.x;
    float4 v = xr[t];
    float s  = v.x + v.y + v.z + v.w;
    float ss = v.x*v.x + v.y*v.y + v.z*v.z + v.w*v.w;
    #pragma unroll
    for (int off = 32; off > 0; off >>= 1) {
        s  += __shfl_down(s, off);
        ss += __shfl_down(ss, off);
    }
    __shared__ float wsum[4], wsq[4], stats[2];
    int wid = t >> 6, lane = t & 63;
    if (lane == 0) { wsum[wid] = s; wsq[wid] = ss; }
    __syncthreads();
    if (t == 0) {
        float S  = wsum[0] + wsum[1] + wsum[2] + wsum[3];
        float SS = wsq[0] + wsq[1] + wsq[2] + wsq[3];
        float mean = S * (1.0f / DIM);
        float var  = SS * (1.0f / DIM) - mean * mean;
        stats[0] = mean;
        stats[1] = rsqrtf(var + 1e-5f);
    }
    __syncthreads();
    float mean = stats[0], rstd = stats[1];
    float4 gv = ((const float4*)g)[t];
    float4 bv = ((const float4*)b)[t];
    bf16x4 o;
    o[0] = (__bf16)((v.x - mean) * rstd * gv.x + bv.x);
    o[1] = (__bf16)((v.y - mean) * rstd * gv.y + bv.y);
    o[2] = (__bf16)((v.z - mean) * rstd * gv.z + bv.z);
    o[3] = (__bf16)((v.w - mean) * rstd * gv.w + bv.w);
    *(bf16x4*)(out + (size_t)row * DIM + t * 4) = o;
}

// ---------------- batched weight transpose: all 6 weights in one dispatch --------
__global__ __launch_bounds__(256) void transpose_all(
    const float* __restrict__ wq, const float* __restrict__ wk,
    const float* __restrict__ wv, const float* __restrict__ wo,
    const float* __restrict__ w1, const float* __restrict__ w2,
    __bf16* __restrict__ wqkt, __bf16* __restrict__ wot,
    __bf16* __restrict__ w1t, __bf16* __restrict__ w2t)
{
    int id = blockIdx.x;
    const float* W; __bf16* Wt; int K, N, txt, tyt;
    if (id < 4096) {
        int seg = id >> 10, r = id & 1023;
        K = DIM; N = DIM;
        txt = r & 31; tyt = r >> 5;
        W  = seg == 0 ? wq : seg == 1 ? wk : seg == 2 ? wv : wo;
        Wt = seg < 3 ? wqkt + (size_t)seg * DIM * DIM : wot;
    } else if (id < 8192) {
        int r = id - 4096;
        K = DIM; N = FFD;
        txt = r & 127; tyt = r >> 7;
        W = w1; Wt = w1t;
    } else {
        int r = id - 8192;
        K = FFD; N = DIM;
        txt = r & 31; tyt = r >> 5;
        W = w2; Wt = w2t;
    }
    __shared__ float tile[32][33];
    int bx = txt * 32, by = tyt * 32;
    int tx = threadIdx.x & 31, ty = threadIdx.x >> 5;
    #pragma unroll
    for (int i = 0; i < 32; i += 8)
        tile[ty + i][tx] = W[(size_t)(by + ty + i) * N + bx + tx];
    __syncthreads();
    #pragma unroll
    for (int i = 0; i < 32; i += 8)
        Wt[(size_t)(bx + ty + i) * K + by + tx] = (__bf16)tile[tx][ty + i];
}

// ---------------- v transpose: qkv[:,2048+d] -> vT[d][row] -----------------------
__global__ __launch_bounds__(256) void transpose_v(
    const __bf16* __restrict__ qkv, __bf16* __restrict__ vT)
{
    __shared__ __bf16 tile[64 * 64];
    int bx = blockIdx.x;  // row tile (ROWS/64)
    int by = blockIdx.y;  // d tile (DIM/64)
    int t = threadIdx.x;
    int r0 = t >> 3, sl = t & 7;
    #pragma unroll
    for (int i = 0; i < 2; i++) {
        int row = i * 32 + r0;
        bf16x8 d = *(const bf16x8*)(qkv + (size_t)(bx * 64 + row) * QKP + 2 * DIM + by * 64 + sl * 8);
        *(bf16x8*)&tile[row * 64 + ((sl ^ (row & 7)) << 3)] = d;
    }
    __syncthreads();
    #pragma unroll
    for (int i = 0; i < 2; i++) {
        int d = i * 32 + r0;
        int rbase = sl * 8;
        bf16x8 o;
        #pragma unroll
        for (int j = 0; j < 8; j++) {
            int rr = rbase + j;
            o[j] = tile[rr * 64 + (((((d >> 3)) ^ (rr & 7)) << 3) | (d & 7))];
        }
        *(bf16x8*)(vT + (size_t)(by * 64 + d) * ROWS + bx * 64 + rbase) = o;
    }
}

// ---------------- gemm_m97: 128x128, m97 2-barrier, 32KB LDS, 4+ blocks/CU -------
// Race-verified rounds 7-8 (__syncthreads drains everything). Kp/NS added for
// split-K (A/Bt pitch Kp, extent K). Inter-block overlap (m114) hides barrier
// drain: 4 blocks/CU at LDS 32KB, VGPR ~100.
#define GBM 128
#define GBN 128
#define GBK 64
template<int MODE, int OUTBF>
__global__ __launch_bounds__(256) void gemm_m97(
    const __bf16* __restrict__ A, const __bf16* __restrict__ Bt,
    void* __restrict__ Cv, const float* __restrict__ bias,
    const float* __restrict__ res, int M, int N, int K, int Kp,
    int NXT, int NYT, int NS)
{
    __shared__ __bf16 Als[GBM * GBK];
    __shared__ __bf16 Bls[GBN * GBK];
    int nb = NXT * NYT;
    int sk = blockIdx.x / nb;
    int tx, ty;
    swz_tile(blockIdx.x % nb, NXT, NYT, tx, ty);
    if (NS > 1) {
        A  += (size_t)sk * K;
        Bt += (size_t)sk * K;
        Cv = (void*)((char*)Cv + (size_t)sk * M * N * (OUTBF ? 2 : 4));
    }
    const int t = threadIdx.x;
    const int lane = t & 63;
    const int w = t >> 6;
    const int wr = w >> 1, wc = w & 1;
    const int bm = ty * GBM, bn = tx * GBN;

    f32x4 acc[4][4] = {};

    const int srow = w * 32 + (lane >> 3);
    const int scol = (lane & 7) * 8;
    const __bf16* gA = A + (size_t)(bm + srow) * Kp + scol;
    const __bf16* gB = Bt + (size_t)(bn + srow) * Kp + scol;
    __bf16* lA = Als + w * 2048;
    __bf16* lB = Bls + w * 2048;

    for (int k0 = 0; k0 < K; k0 += GBK) {
        #pragma unroll
        for (int i = 0; i < 4; i++) {
            __builtin_amdgcn_global_load_lds(
                (const AS1 void*)(gA + (size_t)(i * 8) * Kp + k0),
                (AS3 void*)(lA + i * 512), 16, 0, 0);
            __builtin_amdgcn_global_load_lds(
                (const AS1 void*)(gB + (size_t)(i * 8) * Kp + k0),
                (AS3 void*)(lB + i * 512), 16, 0, 0);
        }
        __syncthreads();
        #pragma unroll
        for (int kk = 0; kk < GBK; kk += 32) {
            bf16x8 af[4], bfr[4];
            #pragma unroll
            for (int m = 0; m < 4; m++)
                af[m] = *(const bf16x8*)&Als[(wr * 64 + m * 16 + (lane & 15)) * GBK + kk + (lane >> 4) * 8];
            #pragma unroll
            for (int n = 0; n < 4; n++)
                bfr[n] = *(const bf16x8*)&Bls[(wc * 64 + n * 16 + (lane & 15)) * GBK + kk + (lane >> 4) * 8];
            #pragma unroll
            for (int m = 0; m < 4; m++)
                #pragma unroll
                for (int n = 0; n < 4; n++)
                    acc[m][n] = __builtin_amdgcn_mfma_f32_16x16x32_bf16(af[m], bfr[n], acc[m][n], 0, 0, 0);
        }
        __syncthreads();
    }
    const int crow0 = bm + wr * 64 + (lane >> 4) * 4;
    const int ccol0 = bn + wc * 64 + (lane & 15);
    #pragma unroll
    for (int m = 0; m < 4; m++) {
        #pragma unroll
        for (int n = 0; n < 4; n++) {
            int col = ccol0 + n * 16;
            #pragma unroll
            for (int r = 0; r < 4; r++) {
                int row = crow0 + m * 16 + r;
                float v = acc[m][n][r];
                if (MODE == 1) v += res[(size_t)row * N + col] + bias[col];
                if (MODE == 2) v = gelu_fast(v + bias[col]);
                if (OUTBF) ((__bf16*)Cv)[(size_t)row * N + col] = (__bf16)v;
                else       ((float*)Cv)[(size_t)row * N + col] = v;
            }
        }
    }
}

// ---------------- gemm256: 256xTBN, BK=64, 8-wave, 8-phase (round-13) ------------
#define TBM 256
#define TBK 64
template<int MODE, int OUTBF, int NBF>
__global__ __launch_bounds__(512) void gemm256(
    const __bf16* __restrict__ A, const __bf16* __restrict__ Bt,
    void* __restrict__ Cv, const float* __restrict__ bias,
    const float* __restrict__ res, int M, int N, int K, int Kp,
    int NXT, int NYT, int NS)
{
    constexpr int ASZ = TBM * TBK;
    constexpr int BSZ = NBF * 64 * TBK;
    constexpr int VM4 = (NBF == 4) ? 4 : 3;
    constexpr int VM8 = (NBF == 4) ? 6 : 5;
    __shared__ __bf16 lds[2 * (ASZ + BSZ)];
    int nb = NXT * NYT;
    int sk = blockIdx.x / nb;
    int tx, ty;
    swz_tile(blockIdx.x % nb, NXT, NYT, tx, ty);
    if (NS > 1) {
        A  += (size_t)sk * K;
        Bt += (size_t)sk * K;
        Cv = (void*)((char*)Cv + (size_t)sk * M * N * (OUTBF ? 2 : 4));
    }
    const int bm = ty * TBM, bn = tx * (NBF * 64);
    const int t = threadIdx.x;
    const int l = t & 63, w = t >> 6;
    const int wm = w >> 2, wn = w & 3;
    const int lm = l & 15, lk = l >> 4;

    f32x4 acc[8][NBF] = {};
    const int nt = K / TBK;
    const int NIT = nt / 2;

    auto Aoff = [&](int bf) { return bf * (ASZ + BSZ); };
    auto Boff = [&](int bf) { return bf * (ASZ + BSZ) + ASZ; };

    const int s7 = lm & 7;
    const int c0 = (lk ^ s7) << 3;
    const int c1 = ((4 ^ lk) ^ s7) << 3;
    const __bf16* pA[2][2] = {
        { &lds[Aoff(0) + (wm * 128 + lm) * 64 + c0], &lds[Aoff(0) + (wm * 128 + lm) * 64 + c1] },
        { &lds[Aoff(1) + (wm * 128 + lm) * 64 + c0], &lds[Aoff(1) + (wm * 128 + lm) * 64 + c1] } };
    const __bf16* pB[2][2] = {
        { &lds[Boff(0) + (wn * (NBF * 16) + lm) * 64 + c0], &lds[Boff(0) + (wn * (NBF * 16) + lm) * 64 + c1] },
        { &lds[Boff(1) + (wn * (NBF * 16) + lm) * 64 + c0], &lds[Boff(1) + (wn * (NBF * 16) + lm) * 64 + c1] } };

    const int srow0 = t >> 3;
    const int scol0 = ((t & 7) ^ (srow0 & 7)) * 8;
    const __bf16* gAb = A + (size_t)(bm + srow0) * Kp + scol0;
    const __bf16* gBb = Bt + (size_t)(bn + srow0) * Kp + scol0;
    const int ldsw = w * 512;

    auto STAGEA_H = [&](int bf, int hf, int kt) {
        #pragma unroll
        for (int i = 0; i < 2; i++) {
            int u = hf * 2 + i;
            __builtin_amdgcn_global_load_lds(
                (const AS1 void*)(gAb + (size_t)(u * 64) * Kp + kt * 64),
                (AS3 void*)(&lds[Aoff(bf) + u * 4096 + ldsw]), 16, 0, 0);
        }
    };
    auto STAGEB_H = [&](int bf, int hf, int kt) {
        const int cnt = (NBF == 4) ? 2 : (hf == 0 ? 2 : 1);
        const int u0  = (NBF == 4) ? hf * 2 : (hf == 0 ? 0 : 2);
        #pragma unroll
        for (int i = 0; i < 2; i++) {
            if (i < cnt) {
                int u = u0 + i;
                __builtin_amdgcn_global_load_lds(
                    (const AS1 void*)(gBb + (size_t)(u * 64) * Kp + kt * 64),
                    (AS3 void*)(&lds[Boff(bf) + u * 4096 + ldsw]), 16, 0, 0);
            }
        }
    };
    auto LDA = [&](int bf, int g, bf16x8* aH) {
        #pragma unroll
        for (int j = 0; j < 4; j++) {
            aH[j * 2 + 0] = *(const bf16x8*)(pA[bf][0] + (g * 4 + j) * 1024);
            aH[j * 2 + 1] = *(const bf16x8*)(pA[bf][1] + (g * 4 + j) * 1024);
        }
    };
    auto LDB0 = [&](int bf, bf16x8* b0) {
        #pragma unroll
        for (int n = 0; n < 2; n++) {
            b0[n * 2 + 0] = *(const bf16x8*)(pB[bf][0] + n * 1024);
            b0[n * 2 + 1] = *(const bf16x8*)(pB[bf][1] + n * 1024);
        }
    };
    auto LDB1 = [&](int bf, bf16x8* b1) {
        #pragma unroll
        for (int n = 0; n < NBF - 2; n++) {
            b1[n * 2 + 0] = *(const bf16x8*)(pB[bf][0] + (2 + n) * 1024);
            b1[n * 2 + 1] = *(const bf16x8*)(pB[bf][1] + (2 + n) * 1024);
        }
    };
    auto MMQ0 = [&](int g, bf16x8* aH, bf16x8* b0) {
        __builtin_amdgcn_s_setprio(1);
        #pragma unroll
        for (int j = 0; j < 4; j++)
            #pragma unroll
            for (int nn = 0; nn < 2; nn++)
                #pragma unroll
                for (int kk = 0; kk < 2; kk++)
                    acc[g * 4 + j][nn] = __builtin_amdgcn_mfma_f32_16x16x32_bf16(
                        aH[j * 2 + kk], b0[nn * 2 + kk], acc[g * 4 + j][nn], 0, 0, 0);
        __builtin_amdgcn_s_setprio(0);
    };
    auto MMQ1 = [&](int g, bf16x8* aH, bf16x8* b1) {
        __builtin_amdgcn_s_setprio(1);
        #pragma unroll
        for (int j = 0; j < 4; j++)
            #pragma unroll
            for (int nn = 0; nn < NBF - 2; nn++)
                #pragma unroll
                for (int kk = 0; kk < 2; kk++)
                    acc[g * 4 + j][2 + nn] = __builtin_amdgcn_mfma_f32_16x16x32_bf16(
                        aH[j * 2 + kk], b1[nn * 2 + kk], acc[g * 4 + j][2 + nn], 0, 0, 0);
        __builtin_amdgcn_s_setprio(0);
    };

    STAGEA_H(0, 0, 0); STAGEA_H(0, 1, 0); STAGEB_H(0, 0, 0); STAGEB_H(0, 1, 0);
    STAGEB_H(1, 0, 1); STAGEB_H(1, 1, 1); STAGEA_H(1, 0, 1);
    vmcnt_wait<VM8>();
    __builtin_amdgcn_s_barrier();

    bf16x8 aH[8], bH0[4], bH1[2 * (NBF - 2)];
    for (int it = 0; it < NIT; it++) {
        int u = 2 * it + 1, T2 = 2 * it + 2, U2 = 2 * it + 3;
        LDA(0, 0, aH); LDB0(0, bH0);
        STAGEA_H(1, 1, u);
        FENCE(); __builtin_amdgcn_s_barrier();
        LGKM0();
        MMQ0(0, aH, bH0);
        FENCE(); __builtin_amdgcn_s_barrier();
        LDB1(0, bH1);
        FENCE(); __builtin_amdgcn_s_barrier();
        LGKM0();
        MMQ1(0, aH, bH1);
        FENCE(); __builtin_amdgcn_s_barrier();
        LDA(0, 1, aH);
        if (T2 < nt) STAGEB_H(0, 0, T2);
        FENCE(); __builtin_amdgcn_s_barrier();
        LGKM0();
        MMQ1(1, aH, bH1);
        FENCE(); __builtin_amdgcn_s_barrier();
        if (T2 < nt) {
            STAGEB_H(0, 1, T2);
            vmcnt_wait<VM4>();
        } else {
            vmcnt_wait<0>();
        }
        __builtin_amdgcn_s_barrier();
        MMQ0(1, aH, bH0);
        FENCE(); __builtin_amdgcn_s_barrier();
        LDA(1, 0, aH); LDB0(1, bH0);
        if (T2 < nt) STAGEA_H(0, 0, T2);
        FENCE(); __builtin_amdgcn_s_barrier();
        LGKM0();
        MMQ0(0, aH, bH0);
        FENCE(); __builtin_amdgcn_s_barrier();
        LDB1(1, bH1);
        if (T2 < nt) STAGEA_H(0, 1, T2);
        FENCE(); __builtin_amdgcn_s_barrier();
        LGKM0();
        MMQ1(0, aH, bH1);
        FENCE(); __builtin_amdgcn_s_barrier();
        LDA(1, 1, aH);
        if (U2 < nt) { STAGEB_H(1, 0, U2); STAGEB_H(1, 1, U2); }
        FENCE(); __builtin_amdgcn_s_barrier();
        LGKM0();
        MMQ1(1, aH, bH1);
        FENCE(); __builtin_amdgcn_s_barrier();
        if (U2 < nt) {
            STAGEA_H(1, 0, U2);
            vmcnt_wait<VM8>();
        } else {
            vmcnt_wait<0>();
        }
        __builtin_amdgcn_s_barrier();
        MMQ0(1, aH, bH0);
        FENCE(); __builtin_amdgcn_s_barrier();
    }

    #pragma unroll
    for (int m = 0; m < 8; m++) {
        #pragma unroll
        for (int n = 0; n < NBF; n++) {
            int col = bn + wn * (NBF * 16) + n * 16 + lm;
            #pragma unroll
            for (int r = 0; r < 4; r++) {
                int row = bm + wm * 128 + m * 16 + lk * 4 + r;
                float v = acc[m][n][r];
                if (MODE == 1) v += res[(size_t)row * N + col] + bias[col];
                if (MODE == 2) v = gelu_fast(v + bias[col]);
                if (OUTBF) ((__bf16*)Cv)[(size_t)row * N + col] = (__bf16)v;
                else       ((float*)Cv)[(size_t)row * N + col] = v;
            }
        }
    }
}

// ---------------- reduceNln: x += bias + sum of NP bf16 partials; optional LN ----
template<int NP, int DOLN>
__global__ __launch_bounds__(256) void reduceNln(
    const __bf16* __restrict__ parts, const float* __restrict__ bias,
    float* __restrict__ x, const float* __restrict__ g,
    const float* __restrict__ b, __bf16* __restrict__ xn)
{
    const size_t PS = (size_t)ROWS * DIM;
    int row = blockIdx.x, t = threadIdx.x;
    size_t base = (size_t)row * DIM + t * 4;
    float4 xr = *(const float4*)(x + base);
    float4 bv = ((const float4*)bias)[t];
    float o0 = xr.x + bv.x, o1 = xr.y + bv.y, o2 = xr.z + bv.z, o3 = xr.w + bv.w;
    #pragma unroll
    for (int s = 0; s < NP; s++) {
        bf16x4 p = *(const bf16x4*)(parts + s * PS + base);
        o0 += (float)p[0]; o1 += (float)p[1]; o2 += (float)p[2]; o3 += (float)p[3];
    }
    float4 o = {o0, o1, o2, o3};
    *(float4*)(x + base) = o;
    if constexpr (DOLN) {
        float s  = o0 + o1 + o2 + o3;
        float ss = o0*o0 + o1*o1 + o2*o2 + o3*o3;
        #pragma unroll
        for (int off = 32; off > 0; off >>= 1) {
            s  += __shfl_down(s, off);
            ss += __shfl_down(ss, off);
        }
        __shared__ float wsum[4], wsq[4], stats[2];
        int wid = t >> 6, lane = t & 63;
        if (lane == 0) { wsum[wid] = s; wsq[wid] = ss; }
        __syncthreads();
        if (t == 0) {
            float S  = wsum[0] + wsum[1] + wsum[2] + wsum[3];
            float SS = wsq[0] + wsq[1] + wsq[2] + wsq[3];
            float mean = S * (1.0f / DIM);
            float var  = SS * (1.0f / DIM) - mean * mean;
            stats[0] = mean;
            stats[1] = rsqrtf(var + 1e-5f);
        }
        __syncthreads();
        float mean = stats[0], rstd = stats[1];
        float4 gv = ((const float4*)g)[t];
        float4 bvv = ((const float4*)b)[t];
        bf16x4 on;
        on[0] = (__bf16)((o0 - mean) * rstd * gv.x + bvv.x);
        on[1] = (__bf16)((o1 - mean) * rstd * gv.y + bvv.y);
        on[2] = (__bf16)((o2 - mean) * rstd * gv.z + bvv.z);
        on[3] = (__bf16)((o3 - mean) * rstd * gv.w + bvv.w);
        *(bf16x4*)(xn + base) = on;
    }
}

// ---------------- attn kernel A: per-chunk KVT_c[e][d] = sum_m v[m][e]ek[m][d] --
__global__ __launch_bounds__(256) void attn_local_m(
    const __bf16* __restrict__ qkv, const __bf16* __restrict__ vTg,
    float* __restrict__ KVT, float* __restrict__ Ksum)
{
    int blk = blockIdx.x;
    int c = blk % NCHK, bh = blk / NCHK;
    int b = bh / NH, h = bh % NH;
    __shared__ __bf16 ek_s[64 * 64];
    __shared__ __bf16 ekT_s[64 * 68];
    __shared__ float ksum_p[4][64];
    int t = threadIdx.x, w = t >> 6, l = t & 63;
    size_t rowbase = (size_t)(b * SEQ + c * CHK);

    {
        int m = t >> 2, dq = t & 3;
        const __bf16* kr = qkv + (rowbase + m) * QKP + DIM + h * DH + dq * 16;
        bf16x8 k0 = *(const bf16x8*)kr;
        bf16x8 k1 = *(const bf16x8*)(kr + 8);
        bf16x8 e0, e1;
        #pragma unroll
        for (int j = 0; j < 8; j++) {
            e0[j] = (__bf16)__expf((float)k0[j]);
            e1[j] = (__bf16)__expf((float)k1[j]);
        }
        *(bf16x8*)&ek_s[swz128(m, dq * 16)] = e0;
        *(bf16x8*)&ek_s[swz128(m, dq * 16 + 8)] = e1;
    }
    __syncthreads();
    {
        float kacc = 0.f;
        #pragma unroll
        for (int g = 0; g < 4; g++) {
            bf16x4 pk;
            #pragma unroll
            for (int j = 0; j < 4; j++) {
                __bf16 e = ek_s[swz128(w * 16 + g * 4 + j, l)];
                pk[j] = e;
                kacc += (float)e;
            }
            *(bf16x4*)&ekT_s[l * 68 + w * 16 + g * 4] = pk;
        }
        ksum_p[w][l] = kacc;
    }
    __syncthreads();
    f32x4 acc[4] = {};
    const __bf16* vbase = vTg + (size_t)(h * DH + w * 16 + (l & 15)) * ROWS
                        + (size_t)b * SEQ + c * CHK + (l >> 4) * 8;
    bf16x8 a0 = *(const bf16x8*)vbase;
    bf16x8 a1 = *(const bf16x8*)(vbase + 32);
    #pragma unroll
    for (int fn = 0; fn < 4; fn++) {
        int rbase = (fn * 16 + (l & 15)) * 68 + (l >> 4) * 8;
        bf16x4 b0a = *(const bf16x4*)&ekT_s[rbase];
        bf16x4 b0b = *(const bf16x4*)&ekT_s[rbase + 4];
        bf16x4 b1a = *(const bf16x4*)&ekT_s[rbase + 32];
        bf16x4 b1b = *(const bf16x4*)&ekT_s[rbase + 36];
        bf16x8 b0, b1;
        #pragma unroll
        for (int j = 0; j < 4; j++) {
            b0[j] = b0a[j]; b0[j + 4] = b0b[j];
            b1[j] = b1a[j]; b1[j + 4] = b1b[j];
        }
        acc[fn] = __builtin_amdgcn_mfma_f32_16x16x32_bf16(a0, b0, acc[fn], 0, 0, 0);
        acc[fn] = __builtin_amdgcn_mfma_f32_16x16x32_bf16(a1, b1, acc[fn], 0, 0, 0);
    }
    float* kvout = KVT + (size_t)(bh * NCHK + c) * (DH * DH);
    #pragma unroll
    for (int fn = 0; fn < 4; fn++)
        #pragma unroll
        for (int r = 0; r < 4; r++)
            kvout[(w * 16 + (l >> 4) * 4 + r) * DH + fn * 16 + (l & 15)] = acc[fn][r];
    if (t < 64) {
        float s = ksum_p[0][t] + ksum_p[1][t] + ksum_p[2][t] + ksum_p[3][t];
        Ksum[(size_t)(bh * NCHK + c) * DH + t] = s;
    }
}

// ---------------- attn kernel B: parallel exclusive prefix over chunks ----------
__global__ __launch_bounds__(256) void attn_scan2(
    float* __restrict__ KV, float* __restrict__ Ksum)
{
    int bh = blockIdx.y;
    int bx = blockIdx.x;
    int t = threadIdx.x;
    if (bx < 16) {
        int elem = bx * 256 + t;
        float run = 0.f;
        for (int c = 0; c < NCHK; c++) {
            float* p = KV + ((size_t)(bh * NCHK + c)) * (DH * DH) + elem;
            float tmp = *p;
            *p = run;
            run += tmp;
        }
    } else if (t < DH) {
        float run = 0.f;
        for (int c = 0; c < NCHK; c++) {
            float* p = Ksum + ((size_t)(bh * NCHK + c)) * DH + t;
            float tmp = *p;
            *p = run;
            run += tmp;
        }
    }
}

// ---------------- attn kernel C: per-chunk output via MFMA ----------------------
__global__ __launch_bounds__(256) void attn_out_m(
    const __bf16* __restrict__ qkv, const __bf16* __restrict__ vTg,
    const float* __restrict__ KVT, const float* __restrict__ Ksum,
    __bf16* __restrict__ ag)
{
    int blk = blockIdx.x;
    int c = blk % NCHK, bh = blk / NCHK;
    int b = bh / NH, h = bh % NH;
    __shared__ __bf16 q_s[64 * 64];
    __shared__ __bf16 ek_s[64 * 64];
    __shared__ __bf16 s_s[64 * 64];
    __shared__ __bf16 kvT_s[64 * 64];
    __shared__ float denom_s[64];
    int t = threadIdx.x, w = t >> 6, l = t & 63;
    size_t rowbase = (size_t)(b * SEQ + c * CHK);

    {
        int i = t >> 2, dq = t & 3;
        const __bf16* qr = qkv + (rowbase + i) * QKP + h * DH + dq * 16;
        bf16x8 q0 = *(const bf16x8*)qr, q1 = *(const bf16x8*)(qr + 8);
        float qf[16];
        #pragma unroll
        for (int j = 0; j < 8; j++) { qf[j] = (float)q0[j]; qf[8 + j] = (float)q1[j]; }
        float mx = qf[0];
        #pragma unroll
        for (int j = 1; j < 16; j++) mx = fmaxf(mx, qf[j]);
        mx = fmaxf(mx, __shfl_xor(mx, 1));
        mx = fmaxf(mx, __shfl_xor(mx, 2));
        float ss = 0.f;
        #pragma unroll
        for (int j = 0; j < 16; j++) { qf[j] = __expf(qf[j] - mx); ss += qf[j]; }
        ss += __shfl_xor(ss, 1);
        ss += __shfl_xor(ss, 2);
        float sc = 0.125f / ss;
        bf16x8 o0, o1;
        #pragma unroll
        for (int j = 0; j < 8; j++) {
            o0[j] = (__bf16)(qf[j] * sc);
            o1[j] = (__bf16)(qf[8 + j] * sc);
        }
        *(bf16x8*)&q_s[swz128(i, dq * 16)] = o0;
        *(bf16x8*)&q_s[swz128(i, dq * 16 + 8)] = o1;
        const float* kp = Ksum + (size_t)(bh * NCHK + c) * DH + dq * 16;
        float dk = 0.f;
        #pragma unroll
        for (int j = 0; j < 16; j++) dk += (qf[j] * sc) * kp[j];
        dk += __shfl_xor(dk, 1);
        dk += __shfl_xor(dk, 2);
        if (dq == 0) denom_s[i] = dk;
    }
    {
        int m = t >> 2, dq = t & 3;
        const __bf16* kr = qkv + (rowbase + m) * QKP + DIM + h * DH + dq * 16;
        bf16x8 k0 = *(const bf16x8*)kr, k1 = *(const bf16x8*)(kr + 8);
        bf16x8 e0, e1;
        #pragma unroll
        for (int j = 0; j < 8; j++) {
            e0[j] = (__bf16)__expf((float)k0[j]);
            e1[j] = (__bf16)__expf((float)k1[j]);
        }
        *(bf16x8*)&ek_s[swz128(m, dq * 16)] = e0;
        *(bf16x8*)&ek_s[swz128(m, dq * 16 + 8)] = e1;
    }
    {
        int e = t >> 2, dq = t & 3;
        const float* kvr = KVT + (size_t)(bh * NCHK + c) * (DH * DH) + e * DH + dq * 16;
        bf16x8 o0, o1;
        #pragma unroll
        for (int j = 0; j < 8; j++) { o0[j] = (__bf16)kvr[j]; o1[j] = (__bf16)kvr[8 + j]; }
        *(bf16x8*)&kvT_s[swz128(e, dq * 16)] = o0;
        *(bf16x8*)&kvT_s[swz128(e, dq * 16 + 8)] = o1;
    }
    __syncthreads();

    bf16x8 bq0 = *(const bf16x8*)&q_s[swz128(w * 16 + (l & 15), (l >> 4) * 8)];
    bf16x8 bq1 = *(const bf16x8*)&q_s[swz128(w * 16 + (l & 15), 32 + (l >> 4) * 8)];
    int i_col = w * 16 + (l & 15);
    float dsum = 0.f;
    #pragma unroll
    for (int fm = 0; fm < 4; fm++) {
        bf16x8 ae0 = *(const bf16x8*)&ek_s[swz128(fm * 16 + (l & 15), (l >> 4) * 8)];
        bf16x8 ae1 = *(const bf16x8*)&ek_s[swz128(fm * 16 + (l & 15), 32 + (l >> 4) * 8)];
        f32x4 z = {};
        z = __builtin_amdgcn_mfma_f32_16x16x32_bf16(ae0, bq0, z, 0, 0, 0);
        z = __builtin_amdgcn_mfma_f32_16x16x32_bf16(ae1, bq1, z, 0, 0, 0);
        bf16x4 pk;
        #pragma unroll
        for (int r = 0; r < 4; r++) {
            int m = fm * 16 + (l >> 4) * 4 + r;
            float v = (m <= i_col) ? z[r] : 0.f;
            pk[r] = (__bf16)v;
            dsum += (float)pk[r];
        }
        *(bf16x4*)&s_s[swz128(i_col, fm * 16 + (l >> 4) * 4)] = pk;
    }
    dsum += __shfl_xor(dsum, 16);
    dsum += __shfl_xor(dsum, 32);
    if (l < 16) denom_s[w * 16 + l] += dsum;

    bf16x8 as0 = *(const bf16x8*)&s_s[swz128(w * 16 + (l & 15), (l >> 4) * 8)];
    bf16x8 as1 = *(const bf16x8*)&s_s[swz128(w * 16 + (l & 15), 32 + (l >> 4) * 8)];
    f32x4 oacc[4] = {};
    #pragma unroll
    for (int fn = 0; fn < 4; fn++) {
        const __bf16* vb = vTg + (size_t)(h * DH + fn * 16 + (l & 15)) * ROWS
                         + (size_t)b * SEQ + c * CHK + (l >> 4) * 8;
        bf16x8 bv0 = *(const bf16x8*)vb;
        bf16x8 bv1 = *(const bf16x8*)(vb + 32);
        bf16x8 bk0 = *(const bf16x8*)&kvT_s[swz128(fn * 16 + (l & 15), (l >> 4) * 8)];
        bf16x8 bk1 = *(const bf16x8*)&kvT_s[swz128(fn * 16 + (l & 15), 32 + (l >> 4) * 8)];
        f32x4 z = oacc[fn];
        z = __builtin_amdgcn_mfma_f32_16x16x32_bf16(as0, bv0, z, 0, 0, 0);
        z = __builtin_amdgcn_mfma_f32_16x16x32_bf16(as1, bv1, z, 0, 0, 0);
        z = __builtin_amdgcn_mfma_f32_16x16x32_bf16(bq0, bk0, z, 0, 0, 0);
        z = __builtin_amdgcn_mfma_f32_16x16x32_bf16(bq1, bk1, z, 0, 0, 0);
        oacc[fn] = z;
    }
    #pragma unroll
    for (int r = 0; r < 4; r++) {
        int i = w * 16 + (l >> 4) * 4 + r;
        float dinv = 1.0f / fmaxf(denom_s[i], 1e-3f);
        #pragma unroll
        for (int fn = 0; fn < 4; fn++)
            ag[(rowbase + i) * DIM + h * DH + fn * 16 + (l & 15)] = (__bf16)(oacc[fn][r] * dinv);
    }
}

// ---------------- launch --------------------------------------------------------
extern "C" void kernel_launch(void* const* d_in, const int* in_sizes, int n_in,
                              void* d_out, int out_size, void* d_ws, size_t ws_size,
                              hipStream_t stream) {
    (void)in_sizes; (void)n_in; (void)out_size; (void)ws_size;
    const float* x_in  = (const float*)d_in[0];
    const float* ln1_g = (const float*)d_in[1];
    const float* ln1_b = (const float*)d_in[2];
    const float* Wq    = (const float*)d_in[3];
    const float* Wk    = (const float*)d_in[4];
    const float* Wv    = (const float*)d_in[5];
    const float* Wo    = (const float*)d_in[6];
    const float* bo    = (const float*)d_in[7];
    const float* ln2_g = (const float*)d_in[8];
    const float* ln2_b = (const float*)d_in[9];
    const float* W1    = (const float*)d_in[10];
    const float* b1    = (const float*)d_in[11];
    const float* W2    = (const float*)d_in[12];
    const float* b2    = (const float*)d_in[13];

    float* x = (float*)d_out;
    const size_t MB = 1024 * 1024;
    char* base = (char*)d_ws;

    __bf16* qkv    = (__bf16*)base;
    __bf16* partsO = (__bf16*)base;              // 2 x 8MB (O-proj NS=2)
    __bf16* h1     = (__bf16*)base;
    __bf16* vTg    = (__bf16*)(base + 24 * MB);
    __bf16* xn     = (__bf16*)(base + 32 * MB);
    __bf16* parts  = (__bf16*)(base + 32 * MB);  // 4 x 8MB (FF2 NS=4)
    __bf16* a      = (__bf16*)(base + 40 * MB);
    float*  KVT    = (float*)(base + 48 * MB);
    float*  Ks     = (float*)(base + 64 * MB);
    __bf16* wqkt   = (__bf16*)(base + 65 * MB);  // 6MB
    __bf16* wot    = (__bf16*)(base + 71 * MB);  // 2MB
    __bf16* w1t    = (__bf16*)(base + 73 * MB);  // 8MB
    __bf16* w2t    = (__bf16*)(base + 81 * MB);  // 8MB

    const size_t SZ = (size_t)ROWS * DIM;
    hipMemcpyAsync(x, x_in, SZ * sizeof(float), hipMemcpyDeviceToDevice, stream);

    dim3 gScan(17, BB * NH);
    dim3 gTv(ROWS / 64, DIM / 64);

    for (int l = 0; l < DEPTH; l++) {
        const float* wq = Wq + (size_t)l * DIM * DIM;
        const float* wk = Wk + (size_t)l * DIM * DIM;
        const float* wv = Wv + (size_t)l * DIM * DIM;
        const float* wo = Wo + (size_t)l * DIM * DIM;
        const float* w1 = W1 + (size_t)l * DIM * FFD;
        const float* w2 = W2 + (size_t)l * FFD * DIM;

        transpose_all<<<12288, 256, 0, stream>>>(wq, wk, wv, wo, w1, w2,
                                                 wqkt, wot, w1t, w2t);

        // pre-norm attention block
        if (l == 0)
            ln_kernel<<<ROWS, 256, 0, stream>>>(x, ln1_g, ln1_b, xn);
        // fused QKV: gemm256 NBF=3 (control arm of the A/B)
        gemm256<0, 1, 3><<<16 * 16, 512, 0, stream>>>(xn, wqkt, qkv, nullptr, nullptr,
                                                      ROWS, QKP, DIM, DIM, 16, 16, 1);
        transpose_v<<<gTv, 256, 0, stream>>>(qkv, vTg);
        attn_local_m<<<BB * NH * NCHK, 256, 0, stream>>>(qkv, vTg, KVT, Ks);
        attn_scan2<<<gScan, 256, 0, stream>>>(KVT, Ks);
        attn_out_m<<<BB * NH * NCHK, 256, 0, stream>>>(qkv, vTg, KVT, Ks, a);
        // O-proj: m97 2-barrier, split-K 2 -> 512 blocks (2/CU)
        gemm_m97<0, 1><<<2 * 8 * 32, 256, 0, stream>>>(a, wot, partsO, nullptr, nullptr,
                                                       ROWS, DIM, DIM / 2, DIM, 8, 32, 2);
        reduceNln<2, 1><<<ROWS, 256, 0, stream>>>(partsO, bo + l * DIM, x,
                                                  ln2_g + l * DIM, ln2_b + l * DIM, xn);

        // pre-norm FF block
        // FF1: m97 2-barrier at 4 blocks/CU (experimental arm of the A/B)
        gemm_m97<2, 1><<<32 * 32, 256, 0, stream>>>(xn, w1t, h1, b1 + l * FFD, nullptr,
                                                    ROWS, FFD, DIM, DIM, 32, 32, 1);
        // FF2: gemm256 split-K 4 (unchanged)
        gemm256<0, 1, 4><<<4 * 16 * 4, 512, 0, stream>>>(h1, w2t, parts, nullptr, nullptr,
                                                         ROWS, DIM, FFD / 4, FFD, 4, 16, 4);
        if (l + 1 < DEPTH)
            reduceNln<4, 1><<<ROWS, 256, 0, stream>>>(parts, b2 + l * DIM, x,
                                                      ln1_g + (l + 1) * DIM,
                                                      ln1_b + (l + 1) * DIM, xn);
        else
            reduceNln<4, 0><<<ROWS, 256, 0, stream>>>(parts, b2 + l * DIM, x,
                                                      nullptr, nullptr, nullptr);
    }
}

// Round 16
// 380.957 us; speedup vs baseline: 1.1045x; 1.1045x over previous
//
#include <hip/hip_runtime.h>
#include <cmath>

#define BB 2
#define SEQ 2048
#define DIM 1024
#define NH 16
#define DH 64
#define DEPTH 2
#define FFD 4096
#define CHK 64
#define NCHK (SEQ/CHK)      // 32
#define ROWS (BB*SEQ)       // 4096
#define QKP (3*DIM)         // fused qkv row pitch (3072)

typedef __bf16 bf16x8 __attribute__((ext_vector_type(8)));
typedef __bf16 bf16x4 __attribute__((ext_vector_type(4)));
typedef float  f32x4  __attribute__((ext_vector_type(4)));

#define AS1 __attribute__((address_space(1)))
#define AS3 __attribute__((address_space(3)))
#define FENCE() asm volatile("" ::: "memory")
#define LGKM0() asm volatile("s_waitcnt lgkmcnt(0)" ::: "memory")

template<int N> __device__ __forceinline__ void vmcnt_wait() {
    if constexpr (N == 0) asm volatile("s_waitcnt vmcnt(0)" ::: "memory");
    else if constexpr (N == 3) asm volatile("s_waitcnt vmcnt(3)" ::: "memory");
    else if constexpr (N == 4) asm volatile("s_waitcnt vmcnt(4)" ::: "memory");
    else if constexpr (N == 5) asm volatile("s_waitcnt vmcnt(5)" ::: "memory");
    else asm volatile("s_waitcnt vmcnt(6)" ::: "memory");
}

// tanh-form GELU: |err| < 1e-3 vs exact; invisible under bf16 rounding
__device__ __forceinline__ float gelu_fast(float x) {
    float x3 = x * x * x;
    float y = 1.5957691216057308f * (x + 0.044715f * x3);
    return x * __builtin_amdgcn_rcpf(1.0f + __expf(-y));
}

// swizzled halfword index into a row-pitch-64hw (128B) bf16 tile
__device__ __forceinline__ int swz128(int row, int col) {
    return row * 64 + (col ^ ((row & 7) << 3));
}

// T1: XCD-contiguous bijective block swizzle (m204) + width-4 column-group order
__device__ __forceinline__ void swz_tile(int bid, int NX, int NY, int& tx, int& ty) {
    int NB = NX * NY;
    int q = NB >> 3, r = NB & 7;
    int xcd = bid & 7, seq = bid >> 3;
    int start = (xcd < r) ? xcd * (q + 1) : r * (q + 1) + (xcd - r) * q;
    int wgid = start + seq;
    int g = 0, rem = wgid;
    int gw = (NX < 4) ? NX : 4;
    while (rem >= gw * NY) {
        rem -= gw * NY; g++;
        int left = NX - 4 * g;
        gw = left < 4 ? left : 4;
    }
    ty = rem / gw;
    tx = 4 * g + rem % gw;
}

// ---------------- LayerNorm (standalone; used only for layer-0 ln1) -------------
__global__ __launch_bounds__(256) void ln_kernel(
    const float* __restrict__ x, const float* __restrict__ g,
    const float* __restrict__ b, __bf16* __restrict__ out)
{
    int row = blockIdx.x;
    const float4* xr = (const float4*)(x + (size_t)row * DIM);
    int t = threadIdx.x;
    float4 v = xr[t];
    float s  = v.x + v.y + v.z + v.w;
    float ss = v.x*v.x + v.y*v.y + v.z*v.z + v.w*v.w;
    #pragma unroll
    for (int off = 32; off > 0; off >>= 1) {
        s  += __shfl_down(s, off);
        ss += __shfl_down(ss, off);
    }
    __shared__ float wsum[4], wsq[4], stats[2];
    int wid = t >> 6, lane = t & 63;
    if (lane == 0) { wsum[wid] = s; wsq[wid] = ss; }
    __syncthreads();
    if (t == 0) {
        float S  = wsum[0] + wsum[1] + wsum[2] + wsum[3];
        float SS = wsq[0] + wsq[1] + wsq[2] + wsq[3];
        float mean = S * (1.0f / DIM);
        float var  = SS * (1.0f / DIM) - mean * mean;
        stats[0] = mean;
        stats[1] = rsqrtf(var + 1e-5f);
    }
    __syncthreads();
    float mean = stats[0], rstd = stats[1];
    float4 gv = ((const float4*)g)[t];
    float4 bv = ((const float4*)b)[t];
    bf16x4 o;
    o[0] = (__bf16)((v.x - mean) * rstd * gv.x + bv.x);
    o[1] = (__bf16)((v.y - mean) * rstd * gv.y + bv.y);
    o[2] = (__bf16)((v.z - mean) * rstd * gv.z + bv.z);
    o[3] = (__bf16)((v.w - mean) * rstd * gv.w + bv.w);
    *(bf16x4*)(out + (size_t)row * DIM + t * 4) = o;
}

// ---------------- batched weight transpose: all 6 weights in one dispatch --------
__global__ __launch_bounds__(256) void transpose_all(
    const float* __restrict__ wq, const float* __restrict__ wk,
    const float* __restrict__ wv, const float* __restrict__ wo,
    const float* __restrict__ w1, const float* __restrict__ w2,
    __bf16* __restrict__ wqkt, __bf16* __restrict__ wot,
    __bf16* __restrict__ w1t, __bf16* __restrict__ w2t)
{
    int id = blockIdx.x;
    const float* W; __bf16* Wt; int K, N, txt, tyt;
    if (id < 4096) {
        int seg = id >> 10, r = id & 1023;
        K = DIM; N = DIM;
        txt = r & 31; tyt = r >> 5;
        W  = seg == 0 ? wq : seg == 1 ? wk : seg == 2 ? wv : wo;
        Wt = seg < 3 ? wqkt + (size_t)seg * DIM * DIM : wot;
    } else if (id < 8192) {
        int r = id - 4096;
        K = DIM; N = FFD;
        txt = r & 127; tyt = r >> 7;
        W = w1; Wt = w1t;
    } else {
        int r = id - 8192;
        K = FFD; N = DIM;
        txt = r & 31; tyt = r >> 5;
        W = w2; Wt = w2t;
    }
    __shared__ float tile[32][33];
    int bx = txt * 32, by = tyt * 32;
    int tx = threadIdx.x & 31, ty = threadIdx.x >> 5;
    #pragma unroll
    for (int i = 0; i < 32; i += 8)
        tile[ty + i][tx] = W[(size_t)(by + ty + i) * N + bx + tx];
    __syncthreads();
    #pragma unroll
    for (int i = 0; i < 32; i += 8)
        Wt[(size_t)(bx + ty + i) * K + by + tx] = (__bf16)tile[tx][ty + i];
}

// ---------------- gemm256: 256xTBN, BK=64, 8-wave, 8-phase (round-13 best) -------
#define TBM 256
#define TBK 64
template<int MODE, int OUTBF, int NBF>
__global__ __launch_bounds__(512) void gemm256(
    const __bf16* __restrict__ A, const __bf16* __restrict__ Bt,
    void* __restrict__ Cv, const float* __restrict__ bias,
    const float* __restrict__ res, int M, int N, int K, int Kp,
    int NXT, int NYT, int NS)
{
    constexpr int ASZ = TBM * TBK;
    constexpr int BSZ = NBF * 64 * TBK;
    constexpr int VM4 = (NBF == 4) ? 4 : 3;
    constexpr int VM8 = (NBF == 4) ? 6 : 5;
    __shared__ __bf16 lds[2 * (ASZ + BSZ)];
    int nb = NXT * NYT;
    int sk = blockIdx.x / nb;
    int tx, ty;
    swz_tile(blockIdx.x % nb, NXT, NYT, tx, ty);
    if (NS > 1) {
        A  += (size_t)sk * K;
        Bt += (size_t)sk * K;
        Cv = (void*)((char*)Cv + (size_t)sk * M * N * (OUTBF ? 2 : 4));
    }
    const int bm = ty * TBM, bn = tx * (NBF * 64);
    const int t = threadIdx.x;
    const int l = t & 63, w = t >> 6;
    const int wm = w >> 2, wn = w & 3;
    const int lm = l & 15, lk = l >> 4;

    f32x4 acc[8][NBF] = {};
    const int nt = K / TBK;
    const int NIT = nt / 2;

    auto Aoff = [&](int bf) { return bf * (ASZ + BSZ); };
    auto Boff = [&](int bf) { return bf * (ASZ + BSZ) + ASZ; };

    const int s7 = lm & 7;
    const int c0 = (lk ^ s7) << 3;
    const int c1 = ((4 ^ lk) ^ s7) << 3;
    const __bf16* pA[2][2] = {
        { &lds[Aoff(0) + (wm * 128 + lm) * 64 + c0], &lds[Aoff(0) + (wm * 128 + lm) * 64 + c1] },
        { &lds[Aoff(1) + (wm * 128 + lm) * 64 + c0], &lds[Aoff(1) + (wm * 128 + lm) * 64 + c1] } };
    const __bf16* pB[2][2] = {
        { &lds[Boff(0) + (wn * (NBF * 16) + lm) * 64 + c0], &lds[Boff(0) + (wn * (NBF * 16) + lm) * 64 + c1] },
        { &lds[Boff(1) + (wn * (NBF * 16) + lm) * 64 + c0], &lds[Boff(1) + (wn * (NBF * 16) + lm) * 64 + c1] } };

    const int srow0 = t >> 3;
    const int scol0 = ((t & 7) ^ (srow0 & 7)) * 8;
    const __bf16* gAb = A + (size_t)(bm + srow0) * Kp + scol0;
    const __bf16* gBb = Bt + (size_t)(bn + srow0) * Kp + scol0;
    const int ldsw = w * 512;

    auto STAGEA_H = [&](int bf, int hf, int kt) {
        #pragma unroll
        for (int i = 0; i < 2; i++) {
            int u = hf * 2 + i;
            __builtin_amdgcn_global_load_lds(
                (const AS1 void*)(gAb + (size_t)(u * 64) * Kp + kt * 64),
                (AS3 void*)(&lds[Aoff(bf) + u * 4096 + ldsw]), 16, 0, 0);
        }
    };
    auto STAGEB_H = [&](int bf, int hf, int kt) {
        const int cnt = (NBF == 4) ? 2 : (hf == 0 ? 2 : 1);
        const int u0  = (NBF == 4) ? hf * 2 : (hf == 0 ? 0 : 2);
        #pragma unroll
        for (int i = 0; i < 2; i++) {
            if (i < cnt) {
                int u = u0 + i;
                __builtin_amdgcn_global_load_lds(
                    (const AS1 void*)(gBb + (size_t)(u * 64) * Kp + kt * 64),
                    (AS3 void*)(&lds[Boff(bf) + u * 4096 + ldsw]), 16, 0, 0);
            }
        }
    };
    auto LDA = [&](int bf, int g, bf16x8* aH) {
        #pragma unroll
        for (int j = 0; j < 4; j++) {
            aH[j * 2 + 0] = *(const bf16x8*)(pA[bf][0] + (g * 4 + j) * 1024);
            aH[j * 2 + 1] = *(const bf16x8*)(pA[bf][1] + (g * 4 + j) * 1024);
        }
    };
    auto LDB0 = [&](int bf, bf16x8* b0) {
        #pragma unroll
        for (int n = 0; n < 2; n++) {
            b0[n * 2 + 0] = *(const bf16x8*)(pB[bf][0] + n * 1024);
            b0[n * 2 + 1] = *(const bf16x8*)(pB[bf][1] + n * 1024);
        }
    };
    auto LDB1 = [&](int bf, bf16x8* b1) {
        #pragma unroll
        for (int n = 0; n < NBF - 2; n++) {
            b1[n * 2 + 0] = *(const bf16x8*)(pB[bf][0] + (2 + n) * 1024);
            b1[n * 2 + 1] = *(const bf16x8*)(pB[bf][1] + (2 + n) * 1024);
        }
    };
    auto MMQ0 = [&](int g, bf16x8* aH, bf16x8* b0) {
        __builtin_amdgcn_s_setprio(1);
        #pragma unroll
        for (int j = 0; j < 4; j++)
            #pragma unroll
            for (int nn = 0; nn < 2; nn++)
                #pragma unroll
                for (int kk = 0; kk < 2; kk++)
                    acc[g * 4 + j][nn] = __builtin_amdgcn_mfma_f32_16x16x32_bf16(
                        aH[j * 2 + kk], b0[nn * 2 + kk], acc[g * 4 + j][nn], 0, 0, 0);
        __builtin_amdgcn_s_setprio(0);
    };
    auto MMQ1 = [&](int g, bf16x8* aH, bf16x8* b1) {
        __builtin_amdgcn_s_setprio(1);
        #pragma unroll
        for (int j = 0; j < 4; j++)
            #pragma unroll
            for (int nn = 0; nn < NBF - 2; nn++)
                #pragma unroll
                for (int kk = 0; kk < 2; kk++)
                    acc[g * 4 + j][2 + nn] = __builtin_amdgcn_mfma_f32_16x16x32_bf16(
                        aH[j * 2 + kk], b1[nn * 2 + kk], acc[g * 4 + j][2 + nn], 0, 0, 0);
        __builtin_amdgcn_s_setprio(0);
    };

    STAGEA_H(0, 0, 0); STAGEA_H(0, 1, 0); STAGEB_H(0, 0, 0); STAGEB_H(0, 1, 0);
    STAGEB_H(1, 0, 1); STAGEB_H(1, 1, 1); STAGEA_H(1, 0, 1);
    vmcnt_wait<VM8>();
    __builtin_amdgcn_s_barrier();

    bf16x8 aH[8], bH0[4], bH1[2 * (NBF - 2)];
    for (int it = 0; it < NIT; it++) {
        int u = 2 * it + 1, T2 = 2 * it + 2, U2 = 2 * it + 3;
        LDA(0, 0, aH); LDB0(0, bH0);
        STAGEA_H(1, 1, u);
        FENCE(); __builtin_amdgcn_s_barrier();
        LGKM0();
        MMQ0(0, aH, bH0);
        FENCE(); __builtin_amdgcn_s_barrier();
        LDB1(0, bH1);
        FENCE(); __builtin_amdgcn_s_barrier();
        LGKM0();
        MMQ1(0, aH, bH1);
        FENCE(); __builtin_amdgcn_s_barrier();
        LDA(0, 1, aH);
        if (T2 < nt) STAGEB_H(0, 0, T2);
        FENCE(); __builtin_amdgcn_s_barrier();
        LGKM0();
        MMQ1(1, aH, bH1);
        FENCE(); __builtin_amdgcn_s_barrier();
        if (T2 < nt) {
            STAGEB_H(0, 1, T2);
            vmcnt_wait<VM4>();
        } else {
            vmcnt_wait<0>();
        }
        __builtin_amdgcn_s_barrier();
        MMQ0(1, aH, bH0);
        FENCE(); __builtin_amdgcn_s_barrier();
        LDA(1, 0, aH); LDB0(1, bH0);
        if (T2 < nt) STAGEA_H(0, 0, T2);
        FENCE(); __builtin_amdgcn_s_barrier();
        LGKM0();
        MMQ0(0, aH, bH0);
        FENCE(); __builtin_amdgcn_s_barrier();
        LDB1(1, bH1);
        if (T2 < nt) STAGEA_H(0, 1, T2);
        FENCE(); __builtin_amdgcn_s_barrier();
        LGKM0();
        MMQ1(0, aH, bH1);
        FENCE(); __builtin_amdgcn_s_barrier();
        LDA(1, 1, aH);
        if (U2 < nt) { STAGEB_H(1, 0, U2); STAGEB_H(1, 1, U2); }
        FENCE(); __builtin_amdgcn_s_barrier();
        LGKM0();
        MMQ1(1, aH, bH1);
        FENCE(); __builtin_amdgcn_s_barrier();
        if (U2 < nt) {
            STAGEA_H(1, 0, U2);
            vmcnt_wait<VM8>();
        } else {
            vmcnt_wait<0>();
        }
        __builtin_amdgcn_s_barrier();
        MMQ0(1, aH, bH0);
        FENCE(); __builtin_amdgcn_s_barrier();
    }

    #pragma unroll
    for (int m = 0; m < 8; m++) {
        #pragma unroll
        for (int n = 0; n < NBF; n++) {
            int col = bn + wn * (NBF * 16) + n * 16 + lm;
            #pragma unroll
            for (int r = 0; r < 4; r++) {
                int row = bm + wm * 128 + m * 16 + lk * 4 + r;
                float v = acc[m][n][r];
                if (MODE == 1) v += res[(size_t)row * N + col] + bias[col];
                if (MODE == 2) v = gelu_fast(v + bias[col]);
                if (OUTBF) ((__bf16*)Cv)[(size_t)row * N + col] = (__bf16)v;
                else       ((float*)Cv)[(size_t)row * N + col] = v;
            }
        }
    }
}

// ---------------- reduce4ln: x += bias + sum of 4 bf16 partials; optional LN -----
template<int DOLN>
__global__ __launch_bounds__(256) void reduce4ln(
    const __bf16* __restrict__ parts, const float* __restrict__ bias,
    float* __restrict__ x, const float* __restrict__ g,
    const float* __restrict__ b, __bf16* __restrict__ xn)
{
    const size_t PS = (size_t)ROWS * DIM;
    int row = blockIdx.x, t = threadIdx.x;
    size_t base = (size_t)row * DIM + t * 4;
    float4 xr = *(const float4*)(x + base);
    float4 bv = ((const float4*)bias)[t];
    float o0 = xr.x + bv.x, o1 = xr.y + bv.y, o2 = xr.z + bv.z, o3 = xr.w + bv.w;
    #pragma unroll
    for (int s = 0; s < 4; s++) {
        bf16x4 p = *(const bf16x4*)(parts + s * PS + base);
        o0 += (float)p[0]; o1 += (float)p[1]; o2 += (float)p[2]; o3 += (float)p[3];
    }
    float4 o = {o0, o1, o2, o3};
    *(float4*)(x + base) = o;
    if constexpr (DOLN) {
        float s  = o0 + o1 + o2 + o3;
        float ss = o0*o0 + o1*o1 + o2*o2 + o3*o3;
        #pragma unroll
        for (int off = 32; off > 0; off >>= 1) {
            s  += __shfl_down(s, off);
            ss += __shfl_down(ss, off);
        }
        __shared__ float wsum[4], wsq[4], stats[2];
        int wid = t >> 6, lane = t & 63;
        if (lane == 0) { wsum[wid] = s; wsq[wid] = ss; }
        __syncthreads();
        if (t == 0) {
            float S  = wsum[0] + wsum[1] + wsum[2] + wsum[3];
            float SS = wsq[0] + wsq[1] + wsq[2] + wsq[3];
            float mean = S * (1.0f / DIM);
            float var  = SS * (1.0f / DIM) - mean * mean;
            stats[0] = mean;
            stats[1] = rsqrtf(var + 1e-5f);
        }
        __syncthreads();
        float mean = stats[0], rstd = stats[1];
        float4 gv = ((const float4*)g)[t];
        float4 bvv = ((const float4*)b)[t];
        bf16x4 on;
        on[0] = (__bf16)((o0 - mean) * rstd * gv.x + bvv.x);
        on[1] = (__bf16)((o1 - mean) * rstd * gv.y + bvv.y);
        on[2] = (__bf16)((o2 - mean) * rstd * gv.z + bvv.z);
        on[3] = (__bf16)((o3 - mean) * rstd * gv.w + bvv.w);
        *(bf16x4*)(xn + base) = on;
    }
}

// ---------------- attn kernel A: KVT_c[e][d] = sum_m v[m][e] ek[m][d] ------------
// Round-16: v staged from qkv + in-LDS transpose (kills transpose_v kernel).
__global__ __launch_bounds__(256) void attn_local_m(
    const __bf16* __restrict__ qkv, float* __restrict__ KVT,
    float* __restrict__ Ksum)
{
    int blk = blockIdx.x;
    int c = blk % NCHK, bh = blk / NCHK;
    int b = bh / NH, h = bh % NH;
    __shared__ __bf16 ek_s[64 * 64];
    __shared__ __bf16 vs_s[64 * 64];
    __shared__ __bf16 ekT_s[64 * 68];
    __shared__ __bf16 vT_s[64 * 68];
    __shared__ float ksum_p[4][64];
    int t = threadIdx.x, w = t >> 6, l = t & 63;
    int lm = l & 15, lk = l >> 4;
    size_t rowbase = (size_t)(b * SEQ + c * CHK);

    {
        int m = t >> 2, dq = t & 3;
        const __bf16* kr = qkv + (rowbase + m) * QKP + DIM + h * DH + dq * 16;
        const __bf16* vr = qkv + (rowbase + m) * QKP + 2 * DIM + h * DH + dq * 16;
        bf16x8 k0 = *(const bf16x8*)kr;
        bf16x8 k1 = *(const bf16x8*)(kr + 8);
        bf16x8 e0, e1;
        #pragma unroll
        for (int j = 0; j < 8; j++) {
            e0[j] = (__bf16)__expf((float)k0[j]);
            e1[j] = (__bf16)__expf((float)k1[j]);
        }
        *(bf16x8*)&ek_s[swz128(m, dq * 16)] = e0;
        *(bf16x8*)&ek_s[swz128(m, dq * 16 + 8)] = e1;
        bf16x8 v0 = *(const bf16x8*)vr;
        bf16x8 v1 = *(const bf16x8*)(vr + 8);
        *(bf16x8*)&vs_s[swz128(m, dq * 16)] = v0;
        *(bf16x8*)&vs_s[swz128(m, dq * 16 + 8)] = v1;
    }
    __syncthreads();
    {
        float kacc = 0.f;
        #pragma unroll
        for (int g = 0; g < 4; g++) {
            bf16x4 pk, pv;
            #pragma unroll
            for (int j = 0; j < 4; j++) {
                __bf16 e = ek_s[swz128(w * 16 + g * 4 + j, l)];
                pk[j] = e;
                kacc += (float)e;
                pv[j] = vs_s[swz128(w * 16 + g * 4 + j, l)];
            }
            *(bf16x4*)&ekT_s[l * 68 + w * 16 + g * 4] = pk;
            *(bf16x4*)&vT_s[l * 68 + w * 16 + g * 4] = pv;
        }
        ksum_p[w][l] = kacc;
    }
    __syncthreads();
    f32x4 acc[4] = {};
    // A-frags from vT_s (row e = w*16+lm, k cols lk*8 and +32), b64-pair pack
    bf16x8 a0, a1;
    {
        int rbA = (w * 16 + lm) * 68 + lk * 8;
        bf16x4 a0a = *(const bf16x4*)&vT_s[rbA];
        bf16x4 a0b = *(const bf16x4*)&vT_s[rbA + 4];
        bf16x4 a1a = *(const bf16x4*)&vT_s[rbA + 32];
        bf16x4 a1b = *(const bf16x4*)&vT_s[rbA + 36];
        #pragma unroll
        for (int j = 0; j < 4; j++) {
            a0[j] = a0a[j]; a0[j + 4] = a0b[j];
            a1[j] = a1a[j]; a1[j + 4] = a1b[j];
        }
    }
    #pragma unroll
    for (int fn = 0; fn < 4; fn++) {
        int rbase = (fn * 16 + lm) * 68 + lk * 8;
        bf16x4 b0a = *(const bf16x4*)&ekT_s[rbase];
        bf16x4 b0b = *(const bf16x4*)&ekT_s[rbase + 4];
        bf16x4 b1a = *(const bf16x4*)&ekT_s[rbase + 32];
        bf16x4 b1b = *(const bf16x4*)&ekT_s[rbase + 36];
        bf16x8 b0, b1;
        #pragma unroll
        for (int j = 0; j < 4; j++) {
            b0[j] = b0a[j]; b0[j + 4] = b0b[j];
            b1[j] = b1a[j]; b1[j + 4] = b1b[j];
        }
        acc[fn] = __builtin_amdgcn_mfma_f32_16x16x32_bf16(a0, b0, acc[fn], 0, 0, 0);
        acc[fn] = __builtin_amdgcn_mfma_f32_16x16x32_bf16(a1, b1, acc[fn], 0, 0, 0);
    }
    float* kvout = KVT + (size_t)(bh * NCHK + c) * (DH * DH);
    #pragma unroll
    for (int fn = 0; fn < 4; fn++)
        #pragma unroll
        for (int r = 0; r < 4; r++)
            kvout[(w * 16 + lk * 4 + r) * DH + fn * 16 + lm] = acc[fn][r];
    if (t < 64) {
        float s = ksum_p[0][t] + ksum_p[1][t] + ksum_p[2][t] + ksum_p[3][t];
        Ksum[(size_t)(bh * NCHK + c) * DH + t] = s;
    }
}

// ---------------- attn kernel B: parallel exclusive prefix over chunks ----------
__global__ __launch_bounds__(256) void attn_scan2(
    float* __restrict__ KV, float* __restrict__ Ksum)
{
    int bh = blockIdx.y;
    int bx = blockIdx.x;
    int t = threadIdx.x;
    if (bx < 16) {
        int elem = bx * 256 + t;
        float run = 0.f;
        for (int c = 0; c < NCHK; c++) {
            float* p = KV + ((size_t)(bh * NCHK + c)) * (DH * DH) + elem;
            float tmp = *p;
            *p = run;
            run += tmp;
        }
    } else if (t < DH) {
        float run = 0.f;
        for (int c = 0; c < NCHK; c++) {
            float* p = Ksum + ((size_t)(bh * NCHK + c)) * DH + t;
            float tmp = *p;
            *p = run;
            run += tmp;
        }
    }
}

// ---------------- attn kernel C: per-chunk output via MFMA ----------------------
// Round-16: v staged from qkv in P0; after P1, vs transposed into ek_s (dead).
__global__ __launch_bounds__(256) void attn_out_m(
    const __bf16* __restrict__ qkv, const float* __restrict__ KVT,
    const float* __restrict__ Ksum, __bf16* __restrict__ ag)
{
    int blk = blockIdx.x;
    int c = blk % NCHK, bh = blk / NCHK;
    int b = bh / NH, h = bh % NH;
    __shared__ __bf16 q_s[64 * 64];
    __shared__ __bf16 ek_s[64 * 64];    // ek in P1; vT in P2
    __shared__ __bf16 s_s[64 * 64];
    __shared__ __bf16 kvT_s[64 * 64];
    __shared__ __bf16 vs_s[64 * 64];
    __shared__ float denom_s[64];
    int t = threadIdx.x, w = t >> 6, l = t & 63;
    int lm = l & 15, lk = l >> 4;
    size_t rowbase = (size_t)(b * SEQ + c * CHK);

    {
        int i = t >> 2, dq = t & 3;
        const __bf16* qr = qkv + (rowbase + i) * QKP + h * DH + dq * 16;
        bf16x8 q0 = *(const bf16x8*)qr, q1 = *(const bf16x8*)(qr + 8);
        float qf[16];
        #pragma unroll
        for (int j = 0; j < 8; j++) { qf[j] = (float)q0[j]; qf[8 + j] = (float)q1[j]; }
        float mx = qf[0];
        #pragma unroll
        for (int j = 1; j < 16; j++) mx = fmaxf(mx, qf[j]);
        mx = fmaxf(mx, __shfl_xor(mx, 1));
        mx = fmaxf(mx, __shfl_xor(mx, 2));
        float ss = 0.f;
        #pragma unroll
        for (int j = 0; j < 16; j++) { qf[j] = __expf(qf[j] - mx); ss += qf[j]; }
        ss += __shfl_xor(ss, 1);
        ss += __shfl_xor(ss, 2);
        float sc = 0.125f / ss;
        bf16x8 o0, o1;
        #pragma unroll
        for (int j = 0; j < 8; j++) {
            o0[j] = (__bf16)(qf[j] * sc);
            o1[j] = (__bf16)(qf[8 + j] * sc);
        }
        *(bf16x8*)&q_s[swz128(i, dq * 16)] = o0;
        *(bf16x8*)&q_s[swz128(i, dq * 16 + 8)] = o1;
        const float* kp = Ksum + (size_t)(bh * NCHK + c) * DH + dq * 16;
        float dk = 0.f;
        #pragma unroll
        for (int j = 0; j < 16; j++) dk += (qf[j] * sc) * kp[j];
        dk += __shfl_xor(dk, 1);
        dk += __shfl_xor(dk, 2);
        if (dq == 0) denom_s[i] = dk;
    }
    {
        int m = t >> 2, dq = t & 3;
        const __bf16* kr = qkv + (rowbase + m) * QKP + DIM + h * DH + dq * 16;
        const __bf16* vr = qkv + (rowbase + m) * QKP + 2 * DIM + h * DH + dq * 16;
        bf16x8 k0 = *(const bf16x8*)kr, k1 = *(const bf16x8*)(kr + 8);
        bf16x8 e0, e1;
        #pragma unroll
        for (int j = 0; j < 8; j++) {
            e0[j] = (__bf16)__expf((float)k0[j]);
            e1[j] = (__bf16)__expf((float)k1[j]);
        }
        *(bf16x8*)&ek_s[swz128(m, dq * 16)] = e0;
        *(bf16x8*)&ek_s[swz128(m, dq * 16 + 8)] = e1;
        bf16x8 v0 = *(const bf16x8*)vr, v1 = *(const bf16x8*)(vr + 8);
        *(bf16x8*)&vs_s[swz128(m, dq * 16)] = v0;
        *(bf16x8*)&vs_s[swz128(m, dq * 16 + 8)] = v1;
    }
    {
        int e = t >> 2, dq = t & 3;
        const float* kvr = KVT + (size_t)(bh * NCHK + c) * (DH * DH) + e * DH + dq * 16;
        bf16x8 o0, o1;
        #pragma unroll
        for (int j = 0; j < 8; j++) { o0[j] = (__bf16)kvr[j]; o1[j] = (__bf16)kvr[8 + j]; }
        *(bf16x8*)&kvT_s[swz128(e, dq * 16)] = o0;
        *(bf16x8*)&kvT_s[swz128(e, dq * 16 + 8)] = o1;
    }
    __syncthreads();

    // P1: S^T (wave w owns i-strip)
    bf16x8 bq0 = *(const bf16x8*)&q_s[swz128(w * 16 + lm, lk * 8)];
    bf16x8 bq1 = *(const bf16x8*)&q_s[swz128(w * 16 + lm, 32 + lk * 8)];
    int i_col = w * 16 + lm;
    float dsum = 0.f;
    #pragma unroll
    for (int fm = 0; fm < 4; fm++) {
        bf16x8 ae0 = *(const bf16x8*)&ek_s[swz128(fm * 16 + lm, lk * 8)];
        bf16x8 ae1 = *(const bf16x8*)&ek_s[swz128(fm * 16 + lm, 32 + lk * 8)];
        f32x4 z = {};
        z = __builtin_amdgcn_mfma_f32_16x16x32_bf16(ae0, bq0, z, 0, 0, 0);
        z = __builtin_amdgcn_mfma_f32_16x16x32_bf16(ae1, bq1, z, 0, 0, 0);
        bf16x4 pk;
        #pragma unroll
        for (int r = 0; r < 4; r++) {
            int m = fm * 16 + lk * 4 + r;
            float v = (m <= i_col) ? z[r] : 0.f;
            pk[r] = (__bf16)v;
            dsum += (float)pk[r];
        }
        *(bf16x4*)&s_s[swz128(i_col, fm * 16 + lk * 4)] = pk;
    }
    dsum += __shfl_xor(dsum, 16);
    dsum += __shfl_xor(dsum, 32);
    if (l < 16) denom_s[w * 16 + l] += dsum;

    // transpose vs -> ek_s (ek dead after P1); all waves must finish P1 ek reads
    __syncthreads();
    {
        #pragma unroll
        for (int g = 0; g < 4; g++) {
            bf16x4 pv;
            #pragma unroll
            for (int j = 0; j < 4; j++)
                pv[j] = vs_s[swz128(w * 16 + g * 4 + j, l)];
            *(bf16x4*)&ek_s[swz128(l, w * 16 + g * 4)] = pv;
        }
    }
    __syncthreads();

    // P2: O = S@V + Q@KVprev (V from transposed ek_s)
    bf16x8 as0 = *(const bf16x8*)&s_s[swz128(w * 16 + lm, lk * 8)];
    bf16x8 as1 = *(const bf16x8*)&s_s[swz128(w * 16 + lm, 32 + lk * 8)];
    f32x4 oacc[4] = {};
    #pragma unroll
    for (int fn = 0; fn < 4; fn++) {
        bf16x8 bv0 = *(const bf16x8*)&ek_s[swz128(fn * 16 + lm, lk * 8)];
        bf16x8 bv1 = *(const bf16x8*)&ek_s[swz128(fn * 16 + lm, 32 + lk * 8)];
        bf16x8 bk0 = *(const bf16x8*)&kvT_s[swz128(fn * 16 + lm, lk * 8)];
        bf16x8 bk1 = *(const bf16x8*)&kvT_s[swz128(fn * 16 + lm, 32 + lk * 8)];
        f32x4 z = oacc[fn];
        z = __builtin_amdgcn_mfma_f32_16x16x32_bf16(as0, bv0, z, 0, 0, 0);
        z = __builtin_amdgcn_mfma_f32_16x16x32_bf16(as1, bv1, z, 0, 0, 0);
        z = __builtin_amdgcn_mfma_f32_16x16x32_bf16(bq0, bk0, z, 0, 0, 0);
        z = __builtin_amdgcn_mfma_f32_16x16x32_bf16(bq1, bk1, z, 0, 0, 0);
        oacc[fn] = z;
    }
    #pragma unroll
    for (int r = 0; r < 4; r++) {
        int i = w * 16 + lk * 4 + r;
        float dinv = 1.0f / fmaxf(denom_s[i], 1e-3f);
        #pragma unroll
        for (int fn = 0; fn < 4; fn++)
            ag[(rowbase + i) * DIM + h * DH + fn * 16 + lm] = (__bf16)(oacc[fn][r] * dinv);
    }
}

// ---------------- launch --------------------------------------------------------
extern "C" void kernel_launch(void* const* d_in, const int* in_sizes, int n_in,
                              void* d_out, int out_size, void* d_ws, size_t ws_size,
                              hipStream_t stream) {
    (void)in_sizes; (void)n_in; (void)out_size; (void)ws_size;
    const float* x_in  = (const float*)d_in[0];
    const float* ln1_g = (const float*)d_in[1];
    const float* ln1_b = (const float*)d_in[2];
    const float* Wq    = (const float*)d_in[3];
    const float* Wk    = (const float*)d_in[4];
    const float* Wv    = (const float*)d_in[5];
    const float* Wo    = (const float*)d_in[6];
    const float* bo    = (const float*)d_in[7];
    const float* ln2_g = (const float*)d_in[8];
    const float* ln2_b = (const float*)d_in[9];
    const float* W1    = (const float*)d_in[10];
    const float* b1    = (const float*)d_in[11];
    const float* W2    = (const float*)d_in[12];
    const float* b2    = (const float*)d_in[13];

    float* x = (float*)d_out;
    const size_t MB = 1024 * 1024;
    char* base = (char*)d_ws;

    __bf16* qkv    = (__bf16*)base;
    __bf16* partsO = (__bf16*)base;
    __bf16* h1     = (__bf16*)base;
    __bf16* xn     = (__bf16*)(base + 32 * MB);
    __bf16* parts  = (__bf16*)(base + 32 * MB);
    __bf16* a      = (__bf16*)(base + 40 * MB);
    float*  KVT    = (float*)(base + 48 * MB);
    float*  Ks     = (float*)(base + 64 * MB);
    __bf16* wqkt   = (__bf16*)(base + 65 * MB);  // 6MB
    __bf16* wot    = (__bf16*)(base + 71 * MB);  // 2MB
    __bf16* w1t    = (__bf16*)(base + 73 * MB);  // 8MB
    __bf16* w2t    = (__bf16*)(base + 81 * MB);  // 8MB

    const size_t SZ = (size_t)ROWS * DIM;
    hipMemcpyAsync(x, x_in, SZ * sizeof(float), hipMemcpyDeviceToDevice, stream);

    dim3 gScan(17, BB * NH);

    for (int l = 0; l < DEPTH; l++) {
        const float* wq = Wq + (size_t)l * DIM * DIM;
        const float* wk = Wk + (size_t)l * DIM * DIM;
        const float* wv = Wv + (size_t)l * DIM * DIM;
        const float* wo = Wo + (size_t)l * DIM * DIM;
        const float* w1 = W1 + (size_t)l * DIM * FFD;
        const float* w2 = W2 + (size_t)l * FFD * DIM;

        transpose_all<<<12288, 256, 0, stream>>>(wq, wk, wv, wo, w1, w2,
                                                 wqkt, wot, w1t, w2t);

        // pre-norm attention block
        if (l == 0)
            ln_kernel<<<ROWS, 256, 0, stream>>>(x, ln1_g, ln1_b, xn);
        gemm256<0, 1, 3><<<16 * 16, 512, 0, stream>>>(xn, wqkt, qkv, nullptr, nullptr,
                                                      ROWS, QKP, DIM, DIM, 16, 16, 1);
        attn_local_m<<<BB * NH * NCHK, 256, 0, stream>>>(qkv, KVT, Ks);
        attn_scan2<<<gScan, 256, 0, stream>>>(KVT, Ks);
        attn_out_m<<<BB * NH * NCHK, 256, 0, stream>>>(qkv, KVT, Ks, a);
        // O-proj: split-K 4 over K=1024 -> bf16 partials (qkv dead)
        gemm256<0, 1, 4><<<4 * 16 * 4, 512, 0, stream>>>(a, wot, partsO, nullptr, nullptr,
                                                         ROWS, DIM, DIM / 4, DIM, 4, 16, 4);
        reduce4ln<1><<<ROWS, 256, 0, stream>>>(partsO, bo + l * DIM, x,
                                               ln2_g + l * DIM, ln2_b + l * DIM, xn);

        // pre-norm FF block (partsO dead -> h1 aliases)
        gemm256<2, 1, 4><<<16 * 16, 512, 0, stream>>>(xn, w1t, h1, b1 + l * FFD, nullptr,
                                                      ROWS, FFD, DIM, DIM, 16, 16, 1);
        gemm256<0, 1, 4><<<4 * 16 * 4, 512, 0, stream>>>(h1, w2t, parts, nullptr, nullptr,
                                                         ROWS, DIM, FFD / 4, FFD, 4, 16, 4);
        if (l + 1 < DEPTH)
            reduce4ln<1><<<ROWS, 256, 0, stream>>>(parts, b2 + l * DIM, x,
                                                   ln1_g + (l + 1) * DIM,
                                                   ln1_b + (l + 1) * DIM, xn);
        else
            reduce4ln<0><<<ROWS, 256, 0, stream>>>(parts, b2 + l * DIM, x,
                                                   nullptr, nullptr, nullptr);
    }
}

// Round 17
// 360.153 us; speedup vs baseline: 1.1683x; 1.0578x over previous
//
#include <hip/hip_runtime.h>
#include <cmath>

#define BB 2
#define SEQ 2048
#define DIM 1024
#define NH 16
#define DH 64
#define DEPTH 2
#define FFD 4096
#define CHK 64
#define NCHK (SEQ/CHK)      // 32
#define ROWS (BB*SEQ)       // 4096
#define QKP (3*DIM)         // fused qkv row pitch (3072)

typedef __bf16 bf16x8 __attribute__((ext_vector_type(8)));
typedef __bf16 bf16x4 __attribute__((ext_vector_type(4)));
typedef float  f32x4  __attribute__((ext_vector_type(4)));

#define AS1 __attribute__((address_space(1)))
#define AS3 __attribute__((address_space(3)))
#define FENCE() asm volatile("" ::: "memory")
#define LGKM0() asm volatile("s_waitcnt lgkmcnt(0)" ::: "memory")

template<int N> __device__ __forceinline__ void vmcnt_wait() {
    if constexpr (N == 0) asm volatile("s_waitcnt vmcnt(0)" ::: "memory");
    else if constexpr (N == 3) asm volatile("s_waitcnt vmcnt(3)" ::: "memory");
    else if constexpr (N == 4) asm volatile("s_waitcnt vmcnt(4)" ::: "memory");
    else if constexpr (N == 5) asm volatile("s_waitcnt vmcnt(5)" ::: "memory");
    else asm volatile("s_waitcnt vmcnt(6)" ::: "memory");
}

// tanh-form GELU: |err| < 1e-3 vs exact; invisible under bf16 rounding
__device__ __forceinline__ float gelu_fast(float x) {
    float x3 = x * x * x;
    float y = 1.5957691216057308f * (x + 0.044715f * x3);
    return x * __builtin_amdgcn_rcpf(1.0f + __expf(-y));
}

// swizzled halfword index into a row-pitch-64hw (128B) bf16 tile
__device__ __forceinline__ int swz128(int row, int col) {
    return row * 64 + (col ^ ((row & 7) << 3));
}

// T1: XCD-contiguous bijective block swizzle (m204) + width-4 column-group order
__device__ __forceinline__ void swz_tile(int bid, int NX, int NY, int& tx, int& ty) {
    int NB = NX * NY;
    int q = NB >> 3, r = NB & 7;
    int xcd = bid & 7, seq = bid >> 3;
    int start = (xcd < r) ? xcd * (q + 1) : r * (q + 1) + (xcd - r) * q;
    int wgid = start + seq;
    int g = 0, rem = wgid;
    int gw = (NX < 4) ? NX : 4;
    while (rem >= gw * NY) {
        rem -= gw * NY; g++;
        int left = NX - 4 * g;
        gw = left < 4 ? left : 4;
    }
    ty = rem / gw;
    tx = 4 * g + rem % gw;
}

// ---------------- LayerNorm (standalone; used only for layer-0 ln1) -------------
__global__ __launch_bounds__(256) void ln_kernel(
    const float* __restrict__ x, const float* __restrict__ g,
    const float* __restrict__ b, __bf16* __restrict__ out)
{
    int row = blockIdx.x;
    const float4* xr = (const float4*)(x + (size_t)row * DIM);
    int t = threadIdx.x;
    float4 v = xr[t];
    float s  = v.x + v.y + v.z + v.w;
    float ss = v.x*v.x + v.y*v.y + v.z*v.z + v.w*v.w;
    #pragma unroll
    for (int off = 32; off > 0; off >>= 1) {
        s  += __shfl_down(s, off);
        ss += __shfl_down(ss, off);
    }
    __shared__ float wsum[4], wsq[4], stats[2];
    int wid = t >> 6, lane = t & 63;
    if (lane == 0) { wsum[wid] = s; wsq[wid] = ss; }
    __syncthreads();
    if (t == 0) {
        float S  = wsum[0] + wsum[1] + wsum[2] + wsum[3];
        float SS = wsq[0] + wsq[1] + wsq[2] + wsq[3];
        float mean = S * (1.0f / DIM);
        float var  = SS * (1.0f / DIM) - mean * mean;
        stats[0] = mean;
        stats[1] = rsqrtf(var + 1e-5f);
    }
    __syncthreads();
    float mean = stats[0], rstd = stats[1];
    float4 gv = ((const float4*)g)[t];
    float4 bv = ((const float4*)b)[t];
    bf16x4 o;
    o[0] = (__bf16)((v.x - mean) * rstd * gv.x + bv.x);
    o[1] = (__bf16)((v.y - mean) * rstd * gv.y + bv.y);
    o[2] = (__bf16)((v.z - mean) * rstd * gv.z + bv.z);
    o[3] = (__bf16)((v.w - mean) * rstd * gv.w + bv.w);
    *(bf16x4*)(out + (size_t)row * DIM + t * 4) = o;
}

// ---------------- batched weight transpose: all 6 weights in one dispatch --------
__global__ __launch_bounds__(256) void transpose_all(
    const float* __restrict__ wq, const float* __restrict__ wk,
    const float* __restrict__ wv, const float* __restrict__ wo,
    const float* __restrict__ w1, const float* __restrict__ w2,
    __bf16* __restrict__ wqkt, __bf16* __restrict__ wot,
    __bf16* __restrict__ w1t, __bf16* __restrict__ w2t)
{
    int id = blockIdx.x;
    const float* W; __bf16* Wt; int K, N, txt, tyt;
    if (id < 4096) {
        int seg = id >> 10, r = id & 1023;
        K = DIM; N = DIM;
        txt = r & 31; tyt = r >> 5;
        W  = seg == 0 ? wq : seg == 1 ? wk : seg == 2 ? wv : wo;
        Wt = seg < 3 ? wqkt + (size_t)seg * DIM * DIM : wot;
    } else if (id < 8192) {
        int r = id - 4096;
        K = DIM; N = FFD;
        txt = r & 127; tyt = r >> 7;
        W = w1; Wt = w1t;
    } else {
        int r = id - 8192;
        K = FFD; N = DIM;
        txt = r & 31; tyt = r >> 5;
        W = w2; Wt = w2t;
    }
    __shared__ float tile[32][33];
    int bx = txt * 32, by = tyt * 32;
    int tx = threadIdx.x & 31, ty = threadIdx.x >> 5;
    #pragma unroll
    for (int i = 0; i < 32; i += 8)
        tile[ty + i][tx] = W[(size_t)(by + ty + i) * N + bx + tx];
    __syncthreads();
    #pragma unroll
    for (int i = 0; i < 32; i += 8)
        Wt[(size_t)(bx + ty + i) * K + by + tx] = (__bf16)tile[tx][ty + i];
}

// ---------------- gemm256: 256xTBN, BK=64, 8-wave, 8-phase (round-13 best) -------
#define TBM 256
#define TBK 64
template<int MODE, int OUTBF, int NBF>
__global__ __launch_bounds__(512) void gemm256(
    const __bf16* __restrict__ A, const __bf16* __restrict__ Bt,
    void* __restrict__ Cv, const float* __restrict__ bias,
    const float* __restrict__ res, int M, int N, int K, int Kp,
    int NXT, int NYT, int NS)
{
    constexpr int ASZ = TBM * TBK;
    constexpr int BSZ = NBF * 64 * TBK;
    constexpr int VM4 = (NBF == 4) ? 4 : 3;
    constexpr int VM8 = (NBF == 4) ? 6 : 5;
    __shared__ __bf16 lds[2 * (ASZ + BSZ)];
    int nb = NXT * NYT;
    int sk = blockIdx.x / nb;
    int tx, ty;
    swz_tile(blockIdx.x % nb, NXT, NYT, tx, ty);
    if (NS > 1) {
        A  += (size_t)sk * K;
        Bt += (size_t)sk * K;
        Cv = (void*)((char*)Cv + (size_t)sk * M * N * (OUTBF ? 2 : 4));
    }
    const int bm = ty * TBM, bn = tx * (NBF * 64);
    const int t = threadIdx.x;
    const int l = t & 63, w = t >> 6;
    const int wm = w >> 2, wn = w & 3;
    const int lm = l & 15, lk = l >> 4;

    f32x4 acc[8][NBF] = {};
    const int nt = K / TBK;
    const int NIT = nt / 2;

    auto Aoff = [&](int bf) { return bf * (ASZ + BSZ); };
    auto Boff = [&](int bf) { return bf * (ASZ + BSZ) + ASZ; };

    const int s7 = lm & 7;
    const int c0 = (lk ^ s7) << 3;
    const int c1 = ((4 ^ lk) ^ s7) << 3;
    const __bf16* pA[2][2] = {
        { &lds[Aoff(0) + (wm * 128 + lm) * 64 + c0], &lds[Aoff(0) + (wm * 128 + lm) * 64 + c1] },
        { &lds[Aoff(1) + (wm * 128 + lm) * 64 + c0], &lds[Aoff(1) + (wm * 128 + lm) * 64 + c1] } };
    const __bf16* pB[2][2] = {
        { &lds[Boff(0) + (wn * (NBF * 16) + lm) * 64 + c0], &lds[Boff(0) + (wn * (NBF * 16) + lm) * 64 + c1] },
        { &lds[Boff(1) + (wn * (NBF * 16) + lm) * 64 + c0], &lds[Boff(1) + (wn * (NBF * 16) + lm) * 64 + c1] } };

    const int srow0 = t >> 3;
    const int scol0 = ((t & 7) ^ (srow0 & 7)) * 8;
    const __bf16* gAb = A + (size_t)(bm + srow0) * Kp + scol0;
    const __bf16* gBb = Bt + (size_t)(bn + srow0) * Kp + scol0;
    const int ldsw = w * 512;

    auto STAGEA_H = [&](int bf, int hf, int kt) {
        #pragma unroll
        for (int i = 0; i < 2; i++) {
            int u = hf * 2 + i;
            __builtin_amdgcn_global_load_lds(
                (const AS1 void*)(gAb + (size_t)(u * 64) * Kp + kt * 64),
                (AS3 void*)(&lds[Aoff(bf) + u * 4096 + ldsw]), 16, 0, 0);
        }
    };
    auto STAGEB_H = [&](int bf, int hf, int kt) {
        const int cnt = (NBF == 4) ? 2 : (hf == 0 ? 2 : 1);
        const int u0  = (NBF == 4) ? hf * 2 : (hf == 0 ? 0 : 2);
        #pragma unroll
        for (int i = 0; i < 2; i++) {
            if (i < cnt) {
                int u = u0 + i;
                __builtin_amdgcn_global_load_lds(
                    (const AS1 void*)(gBb + (size_t)(u * 64) * Kp + kt * 64),
                    (AS3 void*)(&lds[Boff(bf) + u * 4096 + ldsw]), 16, 0, 0);
            }
        }
    };
    auto LDA = [&](int bf, int g, bf16x8* aH) {
        #pragma unroll
        for (int j = 0; j < 4; j++) {
            aH[j * 2 + 0] = *(const bf16x8*)(pA[bf][0] + (g * 4 + j) * 1024);
            aH[j * 2 + 1] = *(const bf16x8*)(pA[bf][1] + (g * 4 + j) * 1024);
        }
    };
    auto LDB0 = [&](int bf, bf16x8* b0) {
        #pragma unroll
        for (int n = 0; n < 2; n++) {
            b0[n * 2 + 0] = *(const bf16x8*)(pB[bf][0] + n * 1024);
            b0[n * 2 + 1] = *(const bf16x8*)(pB[bf][1] + n * 1024);
        }
    };
    auto LDB1 = [&](int bf, bf16x8* b1) {
        #pragma unroll
        for (int n = 0; n < NBF - 2; n++) {
            b1[n * 2 + 0] = *(const bf16x8*)(pB[bf][0] + (2 + n) * 1024);
            b1[n * 2 + 1] = *(const bf16x8*)(pB[bf][1] + (2 + n) * 1024);
        }
    };
    auto MMQ0 = [&](int g, bf16x8* aH, bf16x8* b0) {
        __builtin_amdgcn_s_setprio(1);
        #pragma unroll
        for (int j = 0; j < 4; j++)
            #pragma unroll
            for (int nn = 0; nn < 2; nn++)
                #pragma unroll
                for (int kk = 0; kk < 2; kk++)
                    acc[g * 4 + j][nn] = __builtin_amdgcn_mfma_f32_16x16x32_bf16(
                        aH[j * 2 + kk], b0[nn * 2 + kk], acc[g * 4 + j][nn], 0, 0, 0);
        __builtin_amdgcn_s_setprio(0);
    };
    auto MMQ1 = [&](int g, bf16x8* aH, bf16x8* b1) {
        __builtin_amdgcn_s_setprio(1);
        #pragma unroll
        for (int j = 0; j < 4; j++)
            #pragma unroll
            for (int nn = 0; nn < NBF - 2; nn++)
                #pragma unroll
                for (int kk = 0; kk < 2; kk++)
                    acc[g * 4 + j][2 + nn] = __builtin_amdgcn_mfma_f32_16x16x32_bf16(
                        aH[j * 2 + kk], b1[nn * 2 + kk], acc[g * 4 + j][2 + nn], 0, 0, 0);
        __builtin_amdgcn_s_setprio(0);
    };

    STAGEA_H(0, 0, 0); STAGEA_H(0, 1, 0); STAGEB_H(0, 0, 0); STAGEB_H(0, 1, 0);
    STAGEB_H(1, 0, 1); STAGEB_H(1, 1, 1); STAGEA_H(1, 0, 1);
    vmcnt_wait<VM8>();
    __builtin_amdgcn_s_barrier();

    bf16x8 aH[8], bH0[4], bH1[2 * (NBF - 2)];
    for (int it = 0; it < NIT; it++) {
        int u = 2 * it + 1, T2 = 2 * it + 2, U2 = 2 * it + 3;
        LDA(0, 0, aH); LDB0(0, bH0);
        STAGEA_H(1, 1, u);
        FENCE(); __builtin_amdgcn_s_barrier();
        LGKM0();
        MMQ0(0, aH, bH0);
        FENCE(); __builtin_amdgcn_s_barrier();
        LDB1(0, bH1);
        FENCE(); __builtin_amdgcn_s_barrier();
        LGKM0();
        MMQ1(0, aH, bH1);
        FENCE(); __builtin_amdgcn_s_barrier();
        LDA(0, 1, aH);
        if (T2 < nt) STAGEB_H(0, 0, T2);
        FENCE(); __builtin_amdgcn_s_barrier();
        LGKM0();
        MMQ1(1, aH, bH1);
        FENCE(); __builtin_amdgcn_s_barrier();
        if (T2 < nt) {
            STAGEB_H(0, 1, T2);
            vmcnt_wait<VM4>();
        } else {
            vmcnt_wait<0>();
        }
        __builtin_amdgcn_s_barrier();
        MMQ0(1, aH, bH0);
        FENCE(); __builtin_amdgcn_s_barrier();
        LDA(1, 0, aH); LDB0(1, bH0);
        if (T2 < nt) STAGEA_H(0, 0, T2);
        FENCE(); __builtin_amdgcn_s_barrier();
        LGKM0();
        MMQ0(0, aH, bH0);
        FENCE(); __builtin_amdgcn_s_barrier();
        LDB1(1, bH1);
        if (T2 < nt) STAGEA_H(0, 1, T2);
        FENCE(); __builtin_amdgcn_s_barrier();
        LGKM0();
        MMQ1(0, aH, bH1);
        FENCE(); __builtin_amdgcn_s_barrier();
        LDA(1, 1, aH);
        if (U2 < nt) { STAGEB_H(1, 0, U2); STAGEB_H(1, 1, U2); }
        FENCE(); __builtin_amdgcn_s_barrier();
        LGKM0();
        MMQ1(1, aH, bH1);
        FENCE(); __builtin_amdgcn_s_barrier();
        if (U2 < nt) {
            STAGEA_H(1, 0, U2);
            vmcnt_wait<VM8>();
        } else {
            vmcnt_wait<0>();
        }
        __builtin_amdgcn_s_barrier();
        MMQ0(1, aH, bH0);
        FENCE(); __builtin_amdgcn_s_barrier();
    }

    #pragma unroll
    for (int m = 0; m < 8; m++) {
        #pragma unroll
        for (int n = 0; n < NBF; n++) {
            int col = bn + wn * (NBF * 16) + n * 16 + lm;
            #pragma unroll
            for (int r = 0; r < 4; r++) {
                int row = bm + wm * 128 + m * 16 + lk * 4 + r;
                float v = acc[m][n][r];
                if (MODE == 1) v += res[(size_t)row * N + col] + bias[col];
                if (MODE == 2) v = gelu_fast(v + bias[col]);
                if (OUTBF) ((__bf16*)Cv)[(size_t)row * N + col] = (__bf16)v;
                else       ((float*)Cv)[(size_t)row * N + col] = v;
            }
        }
    }
}

// ---------------- reduce4ln: x = xsrc + bias + sum(parts); optional LN -----------
template<int DOLN>
__global__ __launch_bounds__(256) void reduce4ln(
    const __bf16* __restrict__ parts, const float* __restrict__ bias,
    const float* __restrict__ xsrc, float* __restrict__ x,
    const float* __restrict__ g, const float* __restrict__ b,
    __bf16* __restrict__ xn)
{
    const size_t PS = (size_t)ROWS * DIM;
    int row = blockIdx.x, t = threadIdx.x;
    size_t base = (size_t)row * DIM + t * 4;
    float4 xr = *(const float4*)(xsrc + base);
    float4 bv = ((const float4*)bias)[t];
    float o0 = xr.x + bv.x, o1 = xr.y + bv.y, o2 = xr.z + bv.z, o3 = xr.w + bv.w;
    #pragma unroll
    for (int s = 0; s < 4; s++) {
        bf16x4 p = *(const bf16x4*)(parts + s * PS + base);
        o0 += (float)p[0]; o1 += (float)p[1]; o2 += (float)p[2]; o3 += (float)p[3];
    }
    float4 o = {o0, o1, o2, o3};
    *(float4*)(x + base) = o;
    if constexpr (DOLN) {
        float s  = o0 + o1 + o2 + o3;
        float ss = o0*o0 + o1*o1 + o2*o2 + o3*o3;
        #pragma unroll
        for (int off = 32; off > 0; off >>= 1) {
            s  += __shfl_down(s, off);
            ss += __shfl_down(ss, off);
        }
        __shared__ float wsum[4], wsq[4], stats[2];
        int wid = t >> 6, lane = t & 63;
        if (lane == 0) { wsum[wid] = s; wsq[wid] = ss; }
        __syncthreads();
        if (t == 0) {
            float S  = wsum[0] + wsum[1] + wsum[2] + wsum[3];
            float SS = wsq[0] + wsq[1] + wsq[2] + wsq[3];
            float mean = S * (1.0f / DIM);
            float var  = SS * (1.0f / DIM) - mean * mean;
            stats[0] = mean;
            stats[1] = rsqrtf(var + 1e-5f);
        }
        __syncthreads();
        float mean = stats[0], rstd = stats[1];
        float4 gv = ((const float4*)g)[t];
        float4 bvv = ((const float4*)b)[t];
        bf16x4 on;
        on[0] = (__bf16)((o0 - mean) * rstd * gv.x + bvv.x);
        on[1] = (__bf16)((o1 - mean) * rstd * gv.y + bvv.y);
        on[2] = (__bf16)((o2 - mean) * rstd * gv.z + bvv.z);
        on[3] = (__bf16)((o3 - mean) * rstd * gv.w + bvv.w);
        *(bf16x4*)(xn + base) = on;
    }
}

// ---------------- attn kernel A: KVT_c[e][d] = sum_m v[m][e] ek[m][d] (bf16 out) -
__global__ __launch_bounds__(256) void attn_local_m(
    const __bf16* __restrict__ qkv, __bf16* __restrict__ KVT,
    float* __restrict__ Ksum)
{
    int blk = blockIdx.x;
    int c = blk % NCHK, bh = blk / NCHK;
    int b = bh / NH, h = bh % NH;
    __shared__ __bf16 ek_s[64 * 64];
    __shared__ __bf16 vs_s[64 * 64];
    __shared__ __bf16 ekT_s[64 * 68];
    __shared__ __bf16 vT_s[64 * 68];
    __shared__ float ksum_p[4][64];
    int t = threadIdx.x, w = t >> 6, l = t & 63;
    int lm = l & 15, lk = l >> 4;
    size_t rowbase = (size_t)(b * SEQ + c * CHK);

    {
        int m = t >> 2, dq = t & 3;
        const __bf16* kr = qkv + (rowbase + m) * QKP + DIM + h * DH + dq * 16;
        const __bf16* vr = qkv + (rowbase + m) * QKP + 2 * DIM + h * DH + dq * 16;
        bf16x8 k0 = *(const bf16x8*)kr;
        bf16x8 k1 = *(const bf16x8*)(kr + 8);
        bf16x8 e0, e1;
        #pragma unroll
        for (int j = 0; j < 8; j++) {
            e0[j] = (__bf16)__expf((float)k0[j]);
            e1[j] = (__bf16)__expf((float)k1[j]);
        }
        *(bf16x8*)&ek_s[swz128(m, dq * 16)] = e0;
        *(bf16x8*)&ek_s[swz128(m, dq * 16 + 8)] = e1;
        bf16x8 v0 = *(const bf16x8*)vr;
        bf16x8 v1 = *(const bf16x8*)(vr + 8);
        *(bf16x8*)&vs_s[swz128(m, dq * 16)] = v0;
        *(bf16x8*)&vs_s[swz128(m, dq * 16 + 8)] = v1;
    }
    __syncthreads();
    {
        float kacc = 0.f;
        #pragma unroll
        for (int g = 0; g < 4; g++) {
            bf16x4 pk, pv;
            #pragma unroll
            for (int j = 0; j < 4; j++) {
                __bf16 e = ek_s[swz128(w * 16 + g * 4 + j, l)];
                pk[j] = e;
                kacc += (float)e;
                pv[j] = vs_s[swz128(w * 16 + g * 4 + j, l)];
            }
            *(bf16x4*)&ekT_s[l * 68 + w * 16 + g * 4] = pk;
            *(bf16x4*)&vT_s[l * 68 + w * 16 + g * 4] = pv;
        }
        ksum_p[w][l] = kacc;
    }
    __syncthreads();
    f32x4 acc[4] = {};
    bf16x8 a0, a1;
    {
        int rbA = (w * 16 + lm) * 68 + lk * 8;
        bf16x4 a0a = *(const bf16x4*)&vT_s[rbA];
        bf16x4 a0b = *(const bf16x4*)&vT_s[rbA + 4];
        bf16x4 a1a = *(const bf16x4*)&vT_s[rbA + 32];
        bf16x4 a1b = *(const bf16x4*)&vT_s[rbA + 36];
        #pragma unroll
        for (int j = 0; j < 4; j++) {
            a0[j] = a0a[j]; a0[j + 4] = a0b[j];
            a1[j] = a1a[j]; a1[j + 4] = a1b[j];
        }
    }
    #pragma unroll
    for (int fn = 0; fn < 4; fn++) {
        int rbase = (fn * 16 + lm) * 68 + lk * 8;
        bf16x4 b0a = *(const bf16x4*)&ekT_s[rbase];
        bf16x4 b0b = *(const bf16x4*)&ekT_s[rbase + 4];
        bf16x4 b1a = *(const bf16x4*)&ekT_s[rbase + 32];
        bf16x4 b1b = *(const bf16x4*)&ekT_s[rbase + 36];
        bf16x8 b0, b1;
        #pragma unroll
        for (int j = 0; j < 4; j++) {
            b0[j] = b0a[j]; b0[j + 4] = b0b[j];
            b1[j] = b1a[j]; b1[j + 4] = b1b[j];
        }
        acc[fn] = __builtin_amdgcn_mfma_f32_16x16x32_bf16(a0, b0, acc[fn], 0, 0, 0);
        acc[fn] = __builtin_amdgcn_mfma_f32_16x16x32_bf16(a1, b1, acc[fn], 0, 0, 0);
    }
    __bf16* kvout = KVT + (size_t)(bh * NCHK + c) * (DH * DH);
    #pragma unroll
    for (int fn = 0; fn < 4; fn++)
        #pragma unroll
        for (int r = 0; r < 4; r++)
            kvout[(w * 16 + lk * 4 + r) * DH + fn * 16 + lm] = (__bf16)acc[fn][r];
    if (t < 64) {
        float s = ksum_p[0][t] + ksum_p[1][t] + ksum_p[2][t] + ksum_p[3][t];
        Ksum[(size_t)(bh * NCHK + c) * DH + t] = s;
    }
}

// ---------------- attn kernel B: exclusive prefix over chunks (bf16, fp32 run) ---
__global__ __launch_bounds__(256) void attn_scan2(
    __bf16* __restrict__ KV, float* __restrict__ Ksum)
{
    int bh = blockIdx.y;
    int bx = blockIdx.x;
    int t = threadIdx.x;
    if (bx < 16) {
        int elem = bx * 256 + t;
        float run = 0.f;
        for (int c = 0; c < NCHK; c++) {
            __bf16* p = KV + ((size_t)(bh * NCHK + c)) * (DH * DH) + elem;
            float tmp = (float)*p;
            *p = (__bf16)run;
            run += tmp;
        }
    } else if (t < DH) {
        float run = 0.f;
        for (int c = 0; c < NCHK; c++) {
            float* p = Ksum + ((size_t)(bh * NCHK + c)) * DH + t;
            float tmp = *p;
            *p = run;
            run += tmp;
        }
    }
}

// ---------------- attn kernel C: per-chunk output via MFMA ----------------------
__global__ __launch_bounds__(256) void attn_out_m(
    const __bf16* __restrict__ qkv, const __bf16* __restrict__ KVT,
    const float* __restrict__ Ksum, __bf16* __restrict__ ag)
{
    int blk = blockIdx.x;
    int c = blk % NCHK, bh = blk / NCHK;
    int b = bh / NH, h = bh % NH;
    __shared__ __bf16 q_s[64 * 64];
    __shared__ __bf16 ek_s[64 * 64];    // ek in P1; vT in P2
    __shared__ __bf16 s_s[64 * 64];
    __shared__ __bf16 kvT_s[64 * 64];
    __shared__ __bf16 vs_s[64 * 64];
    __shared__ float denom_s[64];
    int t = threadIdx.x, w = t >> 6, l = t & 63;
    int lm = l & 15, lk = l >> 4;
    size_t rowbase = (size_t)(b * SEQ + c * CHK);

    {
        int i = t >> 2, dq = t & 3;
        const __bf16* qr = qkv + (rowbase + i) * QKP + h * DH + dq * 16;
        bf16x8 q0 = *(const bf16x8*)qr, q1 = *(const bf16x8*)(qr + 8);
        float qf[16];
        #pragma unroll
        for (int j = 0; j < 8; j++) { qf[j] = (float)q0[j]; qf[8 + j] = (float)q1[j]; }
        float mx = qf[0];
        #pragma unroll
        for (int j = 1; j < 16; j++) mx = fmaxf(mx, qf[j]);
        mx = fmaxf(mx, __shfl_xor(mx, 1));
        mx = fmaxf(mx, __shfl_xor(mx, 2));
        float ss = 0.f;
        #pragma unroll
        for (int j = 0; j < 16; j++) { qf[j] = __expf(qf[j] - mx); ss += qf[j]; }
        ss += __shfl_xor(ss, 1);
        ss += __shfl_xor(ss, 2);
        float sc = 0.125f / ss;
        bf16x8 o0, o1;
        #pragma unroll
        for (int j = 0; j < 8; j++) {
            o0[j] = (__bf16)(qf[j] * sc);
            o1[j] = (__bf16)(qf[8 + j] * sc);
        }
        *(bf16x8*)&q_s[swz128(i, dq * 16)] = o0;
        *(bf16x8*)&q_s[swz128(i, dq * 16 + 8)] = o1;
        const float* kp = Ksum + (size_t)(bh * NCHK + c) * DH + dq * 16;
        float dk = 0.f;
        #pragma unroll
        for (int j = 0; j < 16; j++) dk += (qf[j] * sc) * kp[j];
        dk += __shfl_xor(dk, 1);
        dk += __shfl_xor(dk, 2);
        if (dq == 0) denom_s[i] = dk;
    }
    {
        int m = t >> 2, dq = t & 3;
        const __bf16* kr = qkv + (rowbase + m) * QKP + DIM + h * DH + dq * 16;
        const __bf16* vr = qkv + (rowbase + m) * QKP + 2 * DIM + h * DH + dq * 16;
        bf16x8 k0 = *(const bf16x8*)kr, k1 = *(const bf16x8*)(kr + 8);
        bf16x8 e0, e1;
        #pragma unroll
        for (int j = 0; j < 8; j++) {
            e0[j] = (__bf16)__expf((float)k0[j]);
            e1[j] = (__bf16)__expf((float)k1[j]);
        }
        *(bf16x8*)&ek_s[swz128(m, dq * 16)] = e0;
        *(bf16x8*)&ek_s[swz128(m, dq * 16 + 8)] = e1;
        bf16x8 v0 = *(const bf16x8*)vr, v1 = *(const bf16x8*)(vr + 8);
        *(bf16x8*)&vs_s[swz128(m, dq * 16)] = v0;
        *(bf16x8*)&vs_s[swz128(m, dq * 16 + 8)] = v1;
    }
    {
        int e = t >> 2, dq = t & 3;
        const __bf16* kvr = KVT + (size_t)(bh * NCHK + c) * (DH * DH) + e * DH + dq * 16;
        bf16x8 o0 = *(const bf16x8*)kvr;
        bf16x8 o1 = *(const bf16x8*)(kvr + 8);
        *(bf16x8*)&kvT_s[swz128(e, dq * 16)] = o0;
        *(bf16x8*)&kvT_s[swz128(e, dq * 16 + 8)] = o1;
    }
    __syncthreads();

    // P1: S^T (wave w owns i-strip)
    bf16x8 bq0 = *(const bf16x8*)&q_s[swz128(w * 16 + lm, lk * 8)];
    bf16x8 bq1 = *(const bf16x8*)&q_s[swz128(w * 16 + lm, 32 + lk * 8)];
    int i_col = w * 16 + lm;
    float dsum = 0.f;
    #pragma unroll
    for (int fm = 0; fm < 4; fm++) {
        bf16x8 ae0 = *(const bf16x8*)&ek_s[swz128(fm * 16 + lm, lk * 8)];
        bf16x8 ae1 = *(const bf16x8*)&ek_s[swz128(fm * 16 + lm, 32 + lk * 8)];
        f32x4 z = {};
        z = __builtin_amdgcn_mfma_f32_16x16x32_bf16(ae0, bq0, z, 0, 0, 0);
        z = __builtin_amdgcn_mfma_f32_16x16x32_bf16(ae1, bq1, z, 0, 0, 0);
        bf16x4 pk;
        #pragma unroll
        for (int r = 0; r < 4; r++) {
            int m = fm * 16 + lk * 4 + r;
            float v = (m <= i_col) ? z[r] : 0.f;
            pk[r] = (__bf16)v;
            dsum += (float)pk[r];
        }
        *(bf16x4*)&s_s[swz128(i_col, fm * 16 + lk * 4)] = pk;
    }
    dsum += __shfl_xor(dsum, 16);
    dsum += __shfl_xor(dsum, 32);
    if (l < 16) denom_s[w * 16 + l] += dsum;

    // transpose vs -> ek_s (ek dead after P1)
    __syncthreads();
    {
        #pragma unroll
        for (int g = 0; g < 4; g++) {
            bf16x4 pv;
            #pragma unroll
            for (int j = 0; j < 4; j++)
                pv[j] = vs_s[swz128(w * 16 + g * 4 + j, l)];
            *(bf16x4*)&ek_s[swz128(l, w * 16 + g * 4)] = pv;
        }
    }
    __syncthreads();

    // P2: O = S@V + Q@KVprev
    bf16x8 as0 = *(const bf16x8*)&s_s[swz128(w * 16 + lm, lk * 8)];
    bf16x8 as1 = *(const bf16x8*)&s_s[swz128(w * 16 + lm, 32 + lk * 8)];
    f32x4 oacc[4] = {};
    #pragma unroll
    for (int fn = 0; fn < 4; fn++) {
        bf16x8 bv0 = *(const bf16x8*)&ek_s[swz128(fn * 16 + lm, lk * 8)];
        bf16x8 bv1 = *(const bf16x8*)&ek_s[swz128(fn * 16 + lm, 32 + lk * 8)];
        bf16x8 bk0 = *(const bf16x8*)&kvT_s[swz128(fn * 16 + lm, lk * 8)];
        bf16x8 bk1 = *(const bf16x8*)&kvT_s[swz128(fn * 16 + lm, 32 + lk * 8)];
        f32x4 z = oacc[fn];
        z = __builtin_amdgcn_mfma_f32_16x16x32_bf16(as0, bv0, z, 0, 0, 0);
        z = __builtin_amdgcn_mfma_f32_16x16x32_bf16(as1, bv1, z, 0, 0, 0);
        z = __builtin_amdgcn_mfma_f32_16x16x32_bf16(bq0, bk0, z, 0, 0, 0);
        z = __builtin_amdgcn_mfma_f32_16x16x32_bf16(bq1, bk1, z, 0, 0, 0);
        oacc[fn] = z;
    }
    #pragma unroll
    for (int r = 0; r < 4; r++) {
        int i = w * 16 + lk * 4 + r;
        float dinv = 1.0f / fmaxf(denom_s[i], 1e-3f);
        #pragma unroll
        for (int fn = 0; fn < 4; fn++)
            ag[(rowbase + i) * DIM + h * DH + fn * 16 + lm] = (__bf16)(oacc[fn][r] * dinv);
    }
}

// ---------------- launch --------------------------------------------------------
extern "C" void kernel_launch(void* const* d_in, const int* in_sizes, int n_in,
                              void* d_out, int out_size, void* d_ws, size_t ws_size,
                              hipStream_t stream) {
    (void)in_sizes; (void)n_in; (void)out_size; (void)ws_size;
    const float* x_in  = (const float*)d_in[0];
    const float* ln1_g = (const float*)d_in[1];
    const float* ln1_b = (const float*)d_in[2];
    const float* Wq    = (const float*)d_in[3];
    const float* Wk    = (const float*)d_in[4];
    const float* Wv    = (const float*)d_in[5];
    const float* Wo    = (const float*)d_in[6];
    const float* bo    = (const float*)d_in[7];
    const float* ln2_g = (const float*)d_in[8];
    const float* ln2_b = (const float*)d_in[9];
    const float* W1    = (const float*)d_in[10];
    const float* b1    = (const float*)d_in[11];
    const float* W2    = (const float*)d_in[12];
    const float* b2    = (const float*)d_in[13];

    float* x = (float*)d_out;
    const size_t MB = 1024 * 1024;
    char* base = (char*)d_ws;

    __bf16* qkv    = (__bf16*)base;
    __bf16* partsO = (__bf16*)base;
    __bf16* h1     = (__bf16*)base;
    __bf16* xn     = (__bf16*)(base + 32 * MB);
    __bf16* parts  = (__bf16*)(base + 32 * MB);
    __bf16* a      = (__bf16*)(base + 40 * MB);
    __bf16* KVT    = (__bf16*)(base + 48 * MB);  // 8MB bf16
    float*  Ks     = (float*)(base + 64 * MB);
    __bf16* wqkt   = (__bf16*)(base + 65 * MB);  // 6MB
    __bf16* wot    = (__bf16*)(base + 71 * MB);  // 2MB
    __bf16* w1t    = (__bf16*)(base + 73 * MB);  // 8MB
    __bf16* w2t    = (__bf16*)(base + 81 * MB);  // 8MB

    dim3 gScan(17, BB * NH);

    for (int l = 0; l < DEPTH; l++) {
        const float* wq = Wq + (size_t)l * DIM * DIM;
        const float* wk = Wk + (size_t)l * DIM * DIM;
        const float* wv = Wv + (size_t)l * DIM * DIM;
        const float* wo = Wo + (size_t)l * DIM * DIM;
        const float* w1 = W1 + (size_t)l * DIM * FFD;
        const float* w2 = W2 + (size_t)l * FFD * DIM;

        transpose_all<<<12288, 256, 0, stream>>>(wq, wk, wv, wo, w1, w2,
                                                 wqkt, wot, w1t, w2t);

        // pre-norm attention block
        if (l == 0)
            ln_kernel<<<ROWS, 256, 0, stream>>>(x_in, ln1_g, ln1_b, xn);
        gemm256<0, 1, 3><<<16 * 16, 512, 0, stream>>>(xn, wqkt, qkv, nullptr, nullptr,
                                                      ROWS, QKP, DIM, DIM, 16, 16, 1);
        attn_local_m<<<BB * NH * NCHK, 256, 0, stream>>>(qkv, KVT, Ks);
        attn_scan2<<<gScan, 256, 0, stream>>>(KVT, Ks);
        attn_out_m<<<BB * NH * NCHK, 256, 0, stream>>>(qkv, KVT, Ks, a);
        // O-proj: split-K 4 over K=1024 -> bf16 partials (qkv dead)
        gemm256<0, 1, 4><<<4 * 16 * 4, 512, 0, stream>>>(a, wot, partsO, nullptr, nullptr,
                                                         ROWS, DIM, DIM / 4, DIM, 4, 16, 4);
        // layer 0 reads the residual source directly from x_in (no memcpy)
        reduce4ln<1><<<ROWS, 256, 0, stream>>>(partsO, bo + l * DIM,
                                               l == 0 ? x_in : x, x,
                                               ln2_g + l * DIM, ln2_b + l * DIM, xn);

        // pre-norm FF block (partsO dead -> h1 aliases)
        gemm256<2, 1, 4><<<16 * 16, 512, 0, stream>>>(xn, w1t, h1, b1 + l * FFD, nullptr,
                                                      ROWS, FFD, DIM, DIM, 16, 16, 1);
        gemm256<0, 1, 4><<<4 * 16 * 4, 512, 0, stream>>>(h1, w2t, parts, nullptr, nullptr,
                                                         ROWS, DIM, FFD / 4, FFD, 4, 16, 4);
        if (l + 1 < DEPTH)
            reduce4ln<1><<<ROWS, 256, 0, stream>>>(parts, b2 + l * DIM, x, x,
                                                   ln1_g + (l + 1) * DIM,
                                                   ln1_b + (l + 1) * DIM, xn);
        else
            reduce4ln<0><<<ROWS, 256, 0, stream>>>(parts, b2 + l * DIM, x, x,
                                                   nullptr, nullptr, nullptr);
    }
}

// Round 18
// 359.324 us; speedup vs baseline: 1.1710x; 1.0023x over previous
//
#include <hip/hip_runtime.h>
#include <cmath>

#define BB 2
#define SEQ 2048
#define DIM 1024
#define NH 16
#define DH 64
#define DEPTH 2
#define FFD 4096
#define CHK 64
#define NCHK (SEQ/CHK)      // 32
#define ROWS (BB*SEQ)       // 4096
#define QKP (3*DIM)         // fused qkv row pitch (3072)

typedef __bf16 bf16x8 __attribute__((ext_vector_type(8)));
typedef __bf16 bf16x4 __attribute__((ext_vector_type(4)));
typedef float  f32x4  __attribute__((ext_vector_type(4)));

#define AS1 __attribute__((address_space(1)))
#define AS3 __attribute__((address_space(3)))
#define FENCE() asm volatile("" ::: "memory")
#define LGKM0() asm volatile("s_waitcnt lgkmcnt(0)" ::: "memory")

template<int N> __device__ __forceinline__ void vmcnt_wait() {
    if constexpr (N == 0) asm volatile("s_waitcnt vmcnt(0)" ::: "memory");
    else if constexpr (N == 3) asm volatile("s_waitcnt vmcnt(3)" ::: "memory");
    else if constexpr (N == 4) asm volatile("s_waitcnt vmcnt(4)" ::: "memory");
    else if constexpr (N == 5) asm volatile("s_waitcnt vmcnt(5)" ::: "memory");
    else asm volatile("s_waitcnt vmcnt(6)" ::: "memory");
}

// tanh-form GELU: |err| < 1e-3 vs exact; invisible under bf16 rounding
__device__ __forceinline__ float gelu_fast(float x) {
    float x3 = x * x * x;
    float y = 1.5957691216057308f * (x + 0.044715f * x3);
    return x * __builtin_amdgcn_rcpf(1.0f + __expf(-y));
}

// swizzled halfword index into a row-pitch-64hw (128B) bf16 tile
__device__ __forceinline__ int swz128(int row, int col) {
    return row * 64 + (col ^ ((row & 7) << 3));
}

// T1: XCD-contiguous bijective block swizzle (m204) + width-4 column-group order
__device__ __forceinline__ void swz_tile(int bid, int NX, int NY, int& tx, int& ty) {
    int NB = NX * NY;
    int q = NB >> 3, r = NB & 7;
    int xcd = bid & 7, seq = bid >> 3;
    int start = (xcd < r) ? xcd * (q + 1) : r * (q + 1) + (xcd - r) * q;
    int wgid = start + seq;
    int g = 0, rem = wgid;
    int gw = (NX < 4) ? NX : 4;
    while (rem >= gw * NY) {
        rem -= gw * NY; g++;
        int left = NX - 4 * g;
        gw = left < 4 ? left : 4;
    }
    ty = rem / gw;
    tx = 4 * g + rem % gw;
}

// ---------------- LayerNorm (standalone; used only for layer-0 ln1) -------------
__global__ __launch_bounds__(256) void ln_kernel(
    const float* __restrict__ x, const float* __restrict__ g,
    const float* __restrict__ b, __bf16* __restrict__ out)
{
    int row = blockIdx.x;
    const float4* xr = (const float4*)(x + (size_t)row * DIM);
    int t = threadIdx.x;
    float4 v = xr[t];
    float s  = v.x + v.y + v.z + v.w;
    float ss = v.x*v.x + v.y*v.y + v.z*v.z + v.w*v.w;
    #pragma unroll
    for (int off = 32; off > 0; off >>= 1) {
        s  += __shfl_down(s, off);
        ss += __shfl_down(ss, off);
    }
    __shared__ float wsum[4], wsq[4], stats[2];
    int wid = t >> 6, lane = t & 63;
    if (lane == 0) { wsum[wid] = s; wsq[wid] = ss; }
    __syncthreads();
    if (t == 0) {
        float S  = wsum[0] + wsum[1] + wsum[2] + wsum[3];
        float SS = wsq[0] + wsq[1] + wsq[2] + wsq[3];
        float mean = S * (1.0f / DIM);
        float var  = SS * (1.0f / DIM) - mean * mean;
        stats[0] = mean;
        stats[1] = rsqrtf(var + 1e-5f);
    }
    __syncthreads();
    float mean = stats[0], rstd = stats[1];
    float4 gv = ((const float4*)g)[t];
    float4 bv = ((const float4*)b)[t];
    bf16x4 o;
    o[0] = (__bf16)((v.x - mean) * rstd * gv.x + bv.x);
    o[1] = (__bf16)((v.y - mean) * rstd * gv.y + bv.y);
    o[2] = (__bf16)((v.z - mean) * rstd * gv.z + bv.z);
    o[3] = (__bf16)((v.w - mean) * rstd * gv.w + bv.w);
    *(bf16x4*)(out + (size_t)row * DIM + t * 4) = o;
}

// ---------------- batched weight transpose, 16B vector stores --------------------
// Region 32(N) x 64(K) per block; write phase packs 8 K-consecutive elems into
// one bf16x8 store (8 threads -> 128B contiguous run). Round-18: replaces the
// scalar-2B-store version (24MB/layer written at 2B granularity).
__global__ __launch_bounds__(256) void transpose_all(
    const float* __restrict__ wq, const float* __restrict__ wk,
    const float* __restrict__ wv, const float* __restrict__ wo,
    const float* __restrict__ w1, const float* __restrict__ w2,
    __bf16* __restrict__ wqkt, __bf16* __restrict__ wot,
    __bf16* __restrict__ w1t, __bf16* __restrict__ w2t)
{
    int id = blockIdx.x;
    const float* W; __bf16* Wt; int K, N, nb, kb;
    if (id < 2048) {                        // wq,wk,wv,wo: N=1024 (32), K=1024 (16)
        int seg = id >> 9, r = id & 511;
        K = DIM; N = DIM;
        nb = r & 31; kb = r >> 5;
        W  = seg == 0 ? wq : seg == 1 ? wk : seg == 2 ? wv : wo;
        Wt = seg < 3 ? wqkt + (size_t)seg * DIM * DIM : wot;
    } else if (id < 4096) {                 // w1: N=4096 (128), K=1024 (16)
        int r = id - 2048;
        K = DIM; N = FFD;
        nb = r & 127; kb = r >> 7;
        W = w1; Wt = w1t;
    } else {                                // w2: N=1024 (32), K=4096 (64)
        int r = id - 4096;
        K = FFD; N = DIM;
        nb = r & 31; kb = r >> 5;
        W = w2; Wt = w2t;
    }
    const int N0 = nb * 32, K0 = kb * 64;
    __shared__ float tile[64][33];
    int t = threadIdx.x;
    {
        int n = t & 31, k0 = t >> 5;        // k0 0..7
        #pragma unroll
        for (int i = 0; i < 8; i++)
            tile[k0 + 8 * i][n] = W[(size_t)(K0 + k0 + 8 * i) * N + N0 + n];
    }
    __syncthreads();
    {
        int n = t >> 3, kq = t & 7;         // n 0..31, kq 0..7
        bf16x8 o;
        #pragma unroll
        for (int j = 0; j < 8; j++)
            o[j] = (__bf16)tile[kq * 8 + j][n];
        *(bf16x8*)(Wt + (size_t)(N0 + n) * K + K0 + kq * 8) = o;
    }
}

// ---------------- gemm256: 256xTBN, BK=64, 8-wave, 8-phase (round-13 best) -------
#define TBM 256
#define TBK 64
template<int MODE, int OUTBF, int NBF>
__global__ __launch_bounds__(512) void gemm256(
    const __bf16* __restrict__ A, const __bf16* __restrict__ Bt,
    void* __restrict__ Cv, const float* __restrict__ bias,
    const float* __restrict__ res, int M, int N, int K, int Kp,
    int NXT, int NYT, int NS)
{
    constexpr int ASZ = TBM * TBK;
    constexpr int BSZ = NBF * 64 * TBK;
    constexpr int VM4 = (NBF == 4) ? 4 : 3;
    constexpr int VM8 = (NBF == 4) ? 6 : 5;
    __shared__ __bf16 lds[2 * (ASZ + BSZ)];
    int nb = NXT * NYT;
    int sk = blockIdx.x / nb;
    int tx, ty;
    swz_tile(blockIdx.x % nb, NXT, NYT, tx, ty);
    if (NS > 1) {
        A  += (size_t)sk * K;
        Bt += (size_t)sk * K;
        Cv = (void*)((char*)Cv + (size_t)sk * M * N * (OUTBF ? 2 : 4));
    }
    const int bm = ty * TBM, bn = tx * (NBF * 64);
    const int t = threadIdx.x;
    const int l = t & 63, w = t >> 6;
    const int wm = w >> 2, wn = w & 3;
    const int lm = l & 15, lk = l >> 4;

    f32x4 acc[8][NBF] = {};
    const int nt = K / TBK;
    const int NIT = nt / 2;

    auto Aoff = [&](int bf) { return bf * (ASZ + BSZ); };
    auto Boff = [&](int bf) { return bf * (ASZ + BSZ) + ASZ; };

    const int s7 = lm & 7;
    const int c0 = (lk ^ s7) << 3;
    const int c1 = ((4 ^ lk) ^ s7) << 3;
    const __bf16* pA[2][2] = {
        { &lds[Aoff(0) + (wm * 128 + lm) * 64 + c0], &lds[Aoff(0) + (wm * 128 + lm) * 64 + c1] },
        { &lds[Aoff(1) + (wm * 128 + lm) * 64 + c0], &lds[Aoff(1) + (wm * 128 + lm) * 64 + c1] } };
    const __bf16* pB[2][2] = {
        { &lds[Boff(0) + (wn * (NBF * 16) + lm) * 64 + c0], &lds[Boff(0) + (wn * (NBF * 16) + lm) * 64 + c1] },
        { &lds[Boff(1) + (wn * (NBF * 16) + lm) * 64 + c0], &lds[Boff(1) + (wn * (NBF * 16) + lm) * 64 + c1] } };

    const int srow0 = t >> 3;
    const int scol0 = ((t & 7) ^ (srow0 & 7)) * 8;
    const __bf16* gAb = A + (size_t)(bm + srow0) * Kp + scol0;
    const __bf16* gBb = Bt + (size_t)(bn + srow0) * Kp + scol0;
    const int ldsw = w * 512;

    auto STAGEA_H = [&](int bf, int hf, int kt) {
        #pragma unroll
        for (int i = 0; i < 2; i++) {
            int u = hf * 2 + i;
            __builtin_amdgcn_global_load_lds(
                (const AS1 void*)(gAb + (size_t)(u * 64) * Kp + kt * 64),
                (AS3 void*)(&lds[Aoff(bf) + u * 4096 + ldsw]), 16, 0, 0);
        }
    };
    auto STAGEB_H = [&](int bf, int hf, int kt) {
        const int cnt = (NBF == 4) ? 2 : (hf == 0 ? 2 : 1);
        const int u0  = (NBF == 4) ? hf * 2 : (hf == 0 ? 0 : 2);
        #pragma unroll
        for (int i = 0; i < 2; i++) {
            if (i < cnt) {
                int u = u0 + i;
                __builtin_amdgcn_global_load_lds(
                    (const AS1 void*)(gBb + (size_t)(u * 64) * Kp + kt * 64),
                    (AS3 void*)(&lds[Boff(bf) + u * 4096 + ldsw]), 16, 0, 0);
            }
        }
    };
    auto LDA = [&](int bf, int g, bf16x8* aH) {
        #pragma unroll
        for (int j = 0; j < 4; j++) {
            aH[j * 2 + 0] = *(const bf16x8*)(pA[bf][0] + (g * 4 + j) * 1024);
            aH[j * 2 + 1] = *(const bf16x8*)(pA[bf][1] + (g * 4 + j) * 1024);
        }
    };
    auto LDB0 = [&](int bf, bf16x8* b0) {
        #pragma unroll
        for (int n = 0; n < 2; n++) {
            b0[n * 2 + 0] = *(const bf16x8*)(pB[bf][0] + n * 1024);
            b0[n * 2 + 1] = *(const bf16x8*)(pB[bf][1] + n * 1024);
        }
    };
    auto LDB1 = [&](int bf, bf16x8* b1) {
        #pragma unroll
        for (int n = 0; n < NBF - 2; n++) {
            b1[n * 2 + 0] = *(const bf16x8*)(pB[bf][0] + (2 + n) * 1024);
            b1[n * 2 + 1] = *(const bf16x8*)(pB[bf][1] + (2 + n) * 1024);
        }
    };
    auto MMQ0 = [&](int g, bf16x8* aH, bf16x8* b0) {
        __builtin_amdgcn_s_setprio(1);
        #pragma unroll
        for (int j = 0; j < 4; j++)
            #pragma unroll
            for (int nn = 0; nn < 2; nn++)
                #pragma unroll
                for (int kk = 0; kk < 2; kk++)
                    acc[g * 4 + j][nn] = __builtin_amdgcn_mfma_f32_16x16x32_bf16(
                        aH[j * 2 + kk], b0[nn * 2 + kk], acc[g * 4 + j][nn], 0, 0, 0);
        __builtin_amdgcn_s_setprio(0);
    };
    auto MMQ1 = [&](int g, bf16x8* aH, bf16x8* b1) {
        __builtin_amdgcn_s_setprio(1);
        #pragma unroll
        for (int j = 0; j < 4; j++)
            #pragma unroll
            for (int nn = 0; nn < NBF - 2; nn++)
                #pragma unroll
                for (int kk = 0; kk < 2; kk++)
                    acc[g * 4 + j][2 + nn] = __builtin_amdgcn_mfma_f32_16x16x32_bf16(
                        aH[j * 2 + kk], b1[nn * 2 + kk], acc[g * 4 + j][2 + nn], 0, 0, 0);
        __builtin_amdgcn_s_setprio(0);
    };

    STAGEA_H(0, 0, 0); STAGEA_H(0, 1, 0); STAGEB_H(0, 0, 0); STAGEB_H(0, 1, 0);
    STAGEB_H(1, 0, 1); STAGEB_H(1, 1, 1); STAGEA_H(1, 0, 1);
    vmcnt_wait<VM8>();
    __builtin_amdgcn_s_barrier();

    bf16x8 aH[8], bH0[4], bH1[2 * (NBF - 2)];
    for (int it = 0; it < NIT; it++) {
        int u = 2 * it + 1, T2 = 2 * it + 2, U2 = 2 * it + 3;
        LDA(0, 0, aH); LDB0(0, bH0);
        STAGEA_H(1, 1, u);
        FENCE(); __builtin_amdgcn_s_barrier();
        LGKM0();
        MMQ0(0, aH, bH0);
        FENCE(); __builtin_amdgcn_s_barrier();
        LDB1(0, bH1);
        FENCE(); __builtin_amdgcn_s_barrier();
        LGKM0();
        MMQ1(0, aH, bH1);
        FENCE(); __builtin_amdgcn_s_barrier();
        LDA(0, 1, aH);
        if (T2 < nt) STAGEB_H(0, 0, T2);
        FENCE(); __builtin_amdgcn_s_barrier();
        LGKM0();
        MMQ1(1, aH, bH1);
        FENCE(); __builtin_amdgcn_s_barrier();
        if (T2 < nt) {
            STAGEB_H(0, 1, T2);
            vmcnt_wait<VM4>();
        } else {
            vmcnt_wait<0>();
        }
        __builtin_amdgcn_s_barrier();
        MMQ0(1, aH, bH0);
        FENCE(); __builtin_amdgcn_s_barrier();
        LDA(1, 0, aH); LDB0(1, bH0);
        if (T2 < nt) STAGEA_H(0, 0, T2);
        FENCE(); __builtin_amdgcn_s_barrier();
        LGKM0();
        MMQ0(0, aH, bH0);
        FENCE(); __builtin_amdgcn_s_barrier();
        LDB1(1, bH1);
        if (T2 < nt) STAGEA_H(0, 1, T2);
        FENCE(); __builtin_amdgcn_s_barrier();
        LGKM0();
        MMQ1(0, aH, bH1);
        FENCE(); __builtin_amdgcn_s_barrier();
        LDA(1, 1, aH);
        if (U2 < nt) { STAGEB_H(1, 0, U2); STAGEB_H(1, 1, U2); }
        FENCE(); __builtin_amdgcn_s_barrier();
        LGKM0();
        MMQ1(1, aH, bH1);
        FENCE(); __builtin_amdgcn_s_barrier();
        if (U2 < nt) {
            STAGEA_H(1, 0, U2);
            vmcnt_wait<VM8>();
        } else {
            vmcnt_wait<0>();
        }
        __builtin_amdgcn_s_barrier();
        MMQ0(1, aH, bH0);
        FENCE(); __builtin_amdgcn_s_barrier();
    }

    #pragma unroll
    for (int m = 0; m < 8; m++) {
        #pragma unroll
        for (int n = 0; n < NBF; n++) {
            int col = bn + wn * (NBF * 16) + n * 16 + lm;
            #pragma unroll
            for (int r = 0; r < 4; r++) {
                int row = bm + wm * 128 + m * 16 + lk * 4 + r;
                float v = acc[m][n][r];
                if (MODE == 1) v += res[(size_t)row * N + col] + bias[col];
                if (MODE == 2) v = gelu_fast(v + bias[col]);
                if (OUTBF) ((__bf16*)Cv)[(size_t)row * N + col] = (__bf16)v;
                else       ((float*)Cv)[(size_t)row * N + col] = v;
            }
        }
    }
}

// ---------------- reduce4ln: x = xsrc + bias + sum(parts); optional LN -----------
template<int DOLN>
__global__ __launch_bounds__(256) void reduce4ln(
    const __bf16* __restrict__ parts, const float* __restrict__ bias,
    const float* __restrict__ xsrc, float* __restrict__ x,
    const float* __restrict__ g, const float* __restrict__ b,
    __bf16* __restrict__ xn)
{
    const size_t PS = (size_t)ROWS * DIM;
    int row = blockIdx.x, t = threadIdx.x;
    size_t base = (size_t)row * DIM + t * 4;
    float4 xr = *(const float4*)(xsrc + base);
    float4 bv = ((const float4*)bias)[t];
    float o0 = xr.x + bv.x, o1 = xr.y + bv.y, o2 = xr.z + bv.z, o3 = xr.w + bv.w;
    #pragma unroll
    for (int s = 0; s < 4; s++) {
        bf16x4 p = *(const bf16x4*)(parts + s * PS + base);
        o0 += (float)p[0]; o1 += (float)p[1]; o2 += (float)p[2]; o3 += (float)p[3];
    }
    float4 o = {o0, o1, o2, o3};
    *(float4*)(x + base) = o;
    if constexpr (DOLN) {
        float s  = o0 + o1 + o2 + o3;
        float ss = o0*o0 + o1*o1 + o2*o2 + o3*o3;
        #pragma unroll
        for (int off = 32; off > 0; off >>= 1) {
            s  += __shfl_down(s, off);
            ss += __shfl_down(ss, off);
        }
        __shared__ float wsum[4], wsq[4], stats[2];
        int wid = t >> 6, lane = t & 63;
        if (lane == 0) { wsum[wid] = s; wsq[wid] = ss; }
        __syncthreads();
        if (t == 0) {
            float S  = wsum[0] + wsum[1] + wsum[2] + wsum[3];
            float SS = wsq[0] + wsq[1] + wsq[2] + wsq[3];
            float mean = S * (1.0f / DIM);
            float var  = SS * (1.0f / DIM) - mean * mean;
            stats[0] = mean;
            stats[1] = rsqrtf(var + 1e-5f);
        }
        __syncthreads();
        float mean = stats[0], rstd = stats[1];
        float4 gv = ((const float4*)g)[t];
        float4 bvv = ((const float4*)b)[t];
        bf16x4 on;
        on[0] = (__bf16)((o0 - mean) * rstd * gv.x + bvv.x);
        on[1] = (__bf16)((o1 - mean) * rstd * gv.y + bvv.y);
        on[2] = (__bf16)((o2 - mean) * rstd * gv.z + bvv.z);
        on[3] = (__bf16)((o3 - mean) * rstd * gv.w + bvv.w);
        *(bf16x4*)(xn + base) = on;
    }
}

// ---------------- attn kernel A: KVT_c[e][d] = sum_m v[m][e] ek[m][d] (bf16 out) -
__global__ __launch_bounds__(256) void attn_local_m(
    const __bf16* __restrict__ qkv, __bf16* __restrict__ KVT,
    float* __restrict__ Ksum)
{
    int blk = blockIdx.x;
    int c = blk % NCHK, bh = blk / NCHK;
    int b = bh / NH, h = bh % NH;
    __shared__ __bf16 ek_s[64 * 64];
    __shared__ __bf16 vs_s[64 * 64];
    __shared__ __bf16 ekT_s[64 * 68];
    __shared__ __bf16 vT_s[64 * 68];
    __shared__ float ksum_p[4][64];
    int t = threadIdx.x, w = t >> 6, l = t & 63;
    int lm = l & 15, lk = l >> 4;
    size_t rowbase = (size_t)(b * SEQ + c * CHK);

    {
        int m = t >> 2, dq = t & 3;
        const __bf16* kr = qkv + (rowbase + m) * QKP + DIM + h * DH + dq * 16;
        const __bf16* vr = qkv + (rowbase + m) * QKP + 2 * DIM + h * DH + dq * 16;
        bf16x8 k0 = *(const bf16x8*)kr;
        bf16x8 k1 = *(const bf16x8*)(kr + 8);
        bf16x8 e0, e1;
        #pragma unroll
        for (int j = 0; j < 8; j++) {
            e0[j] = (__bf16)__expf((float)k0[j]);
            e1[j] = (__bf16)__expf((float)k1[j]);
        }
        *(bf16x8*)&ek_s[swz128(m, dq * 16)] = e0;
        *(bf16x8*)&ek_s[swz128(m, dq * 16 + 8)] = e1;
        bf16x8 v0 = *(const bf16x8*)vr;
        bf16x8 v1 = *(const bf16x8*)(vr + 8);
        *(bf16x8*)&vs_s[swz128(m, dq * 16)] = v0;
        *(bf16x8*)&vs_s[swz128(m, dq * 16 + 8)] = v1;
    }
    __syncthreads();
    {
        float kacc = 0.f;
        #pragma unroll
        for (int g = 0; g < 4; g++) {
            bf16x4 pk, pv;
            #pragma unroll
            for (int j = 0; j < 4; j++) {
                __bf16 e = ek_s[swz128(w * 16 + g * 4 + j, l)];
                pk[j] = e;
                kacc += (float)e;
                pv[j] = vs_s[swz128(w * 16 + g * 4 + j, l)];
            }
            *(bf16x4*)&ekT_s[l * 68 + w * 16 + g * 4] = pk;
            *(bf16x4*)&vT_s[l * 68 + w * 16 + g * 4] = pv;
        }
        ksum_p[w][l] = kacc;
    }
    __syncthreads();
    f32x4 acc[4] = {};
    bf16x8 a0, a1;
    {
        int rbA = (w * 16 + lm) * 68 + lk * 8;
        bf16x4 a0a = *(const bf16x4*)&vT_s[rbA];
        bf16x4 a0b = *(const bf16x4*)&vT_s[rbA + 4];
        bf16x4 a1a = *(const bf16x4*)&vT_s[rbA + 32];
        bf16x4 a1b = *(const bf16x4*)&vT_s[rbA + 36];
        #pragma unroll
        for (int j = 0; j < 4; j++) {
            a0[j] = a0a[j]; a0[j + 4] = a0b[j];
            a1[j] = a1a[j]; a1[j + 4] = a1b[j];
        }
    }
    #pragma unroll
    for (int fn = 0; fn < 4; fn++) {
        int rbase = (fn * 16 + lm) * 68 + lk * 8;
        bf16x4 b0a = *(const bf16x4*)&ekT_s[rbase];
        bf16x4 b0b = *(const bf16x4*)&ekT_s[rbase + 4];
        bf16x4 b1a = *(const bf16x4*)&ekT_s[rbase + 32];
        bf16x4 b1b = *(const bf16x4*)&ekT_s[rbase + 36];
        bf16x8 b0, b1;
        #pragma unroll
        for (int j = 0; j < 4; j++) {
            b0[j] = b0a[j]; b0[j + 4] = b0b[j];
            b1[j] = b1a[j]; b1[j + 4] = b1b[j];
        }
        acc[fn] = __builtin_amdgcn_mfma_f32_16x16x32_bf16(a0, b0, acc[fn], 0, 0, 0);
        acc[fn] = __builtin_amdgcn_mfma_f32_16x16x32_bf16(a1, b1, acc[fn], 0, 0, 0);
    }
    __bf16* kvout = KVT + (size_t)(bh * NCHK + c) * (DH * DH);
    #pragma unroll
    for (int fn = 0; fn < 4; fn++)
        #pragma unroll
        for (int r = 0; r < 4; r++)
            kvout[(w * 16 + lk * 4 + r) * DH + fn * 16 + lm] = (__bf16)acc[fn][r];
    if (t < 64) {
        float s = ksum_p[0][t] + ksum_p[1][t] + ksum_p[2][t] + ksum_p[3][t];
        Ksum[(size_t)(bh * NCHK + c) * DH + t] = s;
    }
}

// ---------------- attn kernel B: exclusive prefix over chunks (bf16, fp32 run) ---
__global__ __launch_bounds__(256) void attn_scan2(
    __bf16* __restrict__ KV, float* __restrict__ Ksum)
{
    int bh = blockIdx.y;
    int bx = blockIdx.x;
    int t = threadIdx.x;
    if (bx < 16) {
        int elem = bx * 256 + t;
        float run = 0.f;
        for (int c = 0; c < NCHK; c++) {
            __bf16* p = KV + ((size_t)(bh * NCHK + c)) * (DH * DH) + elem;
            float tmp = (float)*p;
            *p = (__bf16)run;
            run += tmp;
        }
    } else if (t < DH) {
        float run = 0.f;
        for (int c = 0; c < NCHK; c++) {
            float* p = Ksum + ((size_t)(bh * NCHK + c)) * DH + t;
            float tmp = *p;
            *p = run;
            run += tmp;
        }
    }
}

// ---------------- attn kernel C: per-chunk output via MFMA ----------------------
__global__ __launch_bounds__(256) void attn_out_m(
    const __bf16* __restrict__ qkv, const __bf16* __restrict__ KVT,
    const float* __restrict__ Ksum, __bf16* __restrict__ ag)
{
    int blk = blockIdx.x;
    int c = blk % NCHK, bh = blk / NCHK;
    int b = bh / NH, h = bh % NH;
    __shared__ __bf16 q_s[64 * 64];
    __shared__ __bf16 ek_s[64 * 64];    // ek in P1; vT in P2
    __shared__ __bf16 s_s[64 * 64];
    __shared__ __bf16 kvT_s[64 * 64];
    __shared__ __bf16 vs_s[64 * 64];
    __shared__ float denom_s[64];
    int t = threadIdx.x, w = t >> 6, l = t & 63;
    int lm = l & 15, lk = l >> 4;
    size_t rowbase = (size_t)(b * SEQ + c * CHK);

    {
        int i = t >> 2, dq = t & 3;
        const __bf16* qr = qkv + (rowbase + i) * QKP + h * DH + dq * 16;
        bf16x8 q0 = *(const bf16x8*)qr, q1 = *(const bf16x8*)(qr + 8);
        float qf[16];
        #pragma unroll
        for (int j = 0; j < 8; j++) { qf[j] = (float)q0[j]; qf[8 + j] = (float)q1[j]; }
        float mx = qf[0];
        #pragma unroll
        for (int j = 1; j < 16; j++) mx = fmaxf(mx, qf[j]);
        mx = fmaxf(mx, __shfl_xor(mx, 1));
        mx = fmaxf(mx, __shfl_xor(mx, 2));
        float ss = 0.f;
        #pragma unroll
        for (int j = 0; j < 16; j++) { qf[j] = __expf(qf[j] - mx); ss += qf[j]; }
        ss += __shfl_xor(ss, 1);
        ss += __shfl_xor(ss, 2);
        float sc = 0.125f / ss;
        bf16x8 o0, o1;
        #pragma unroll
        for (int j = 0; j < 8; j++) {
            o0[j] = (__bf16)(qf[j] * sc);
            o1[j] = (__bf16)(qf[8 + j] * sc);
        }
        *(bf16x8*)&q_s[swz128(i, dq * 16)] = o0;
        *(bf16x8*)&q_s[swz128(i, dq * 16 + 8)] = o1;
        const float* kp = Ksum + (size_t)(bh * NCHK + c) * DH + dq * 16;
        float dk = 0.f;
        #pragma unroll
        for (int j = 0; j < 16; j++) dk += (qf[j] * sc) * kp[j];
        dk += __shfl_xor(dk, 1);
        dk += __shfl_xor(dk, 2);
        if (dq == 0) denom_s[i] = dk;
    }
    {
        int m = t >> 2, dq = t & 3;
        const __bf16* kr = qkv + (rowbase + m) * QKP + DIM + h * DH + dq * 16;
        const __bf16* vr = qkv + (rowbase + m) * QKP + 2 * DIM + h * DH + dq * 16;
        bf16x8 k0 = *(const bf16x8*)kr, k1 = *(const bf16x8*)(kr + 8);
        bf16x8 e0, e1;
        #pragma unroll
        for (int j = 0; j < 8; j++) {
            e0[j] = (__bf16)__expf((float)k0[j]);
            e1[j] = (__bf16)__expf((float)k1[j]);
        }
        *(bf16x8*)&ek_s[swz128(m, dq * 16)] = e0;
        *(bf16x8*)&ek_s[swz128(m, dq * 16 + 8)] = e1;
        bf16x8 v0 = *(const bf16x8*)vr, v1 = *(const bf16x8*)(vr + 8);
        *(bf16x8*)&vs_s[swz128(m, dq * 16)] = v0;
        *(bf16x8*)&vs_s[swz128(m, dq * 16 + 8)] = v1;
    }
    {
        int e = t >> 2, dq = t & 3;
        const __bf16* kvr = KVT + (size_t)(bh * NCHK + c) * (DH * DH) + e * DH + dq * 16;
        bf16x8 o0 = *(const bf16x8*)kvr;
        bf16x8 o1 = *(const bf16x8*)(kvr + 8);
        *(bf16x8*)&kvT_s[swz128(e, dq * 16)] = o0;
        *(bf16x8*)&kvT_s[swz128(e, dq * 16 + 8)] = o1;
    }
    __syncthreads();

    // P1: S^T (wave w owns i-strip)
    bf16x8 bq0 = *(const bf16x8*)&q_s[swz128(w * 16 + lm, lk * 8)];
    bf16x8 bq1 = *(const bf16x8*)&q_s[swz128(w * 16 + lm, 32 + lk * 8)];
    int i_col = w * 16 + lm;
    float dsum = 0.f;
    #pragma unroll
    for (int fm = 0; fm < 4; fm++) {
        bf16x8 ae0 = *(const bf16x8*)&ek_s[swz128(fm * 16 + lm, lk * 8)];
        bf16x8 ae1 = *(const bf16x8*)&ek_s[swz128(fm * 16 + lm, 32 + lk * 8)];
        f32x4 z = {};
        z = __builtin_amdgcn_mfma_f32_16x16x32_bf16(ae0, bq0, z, 0, 0, 0);
        z = __builtin_amdgcn_mfma_f32_16x16x32_bf16(ae1, bq1, z, 0, 0, 0);
        bf16x4 pk;
        #pragma unroll
        for (int r = 0; r < 4; r++) {
            int m = fm * 16 + lk * 4 + r;
            float v = (m <= i_col) ? z[r] : 0.f;
            pk[r] = (__bf16)v;
            dsum += (float)pk[r];
        }
        *(bf16x4*)&s_s[swz128(i_col, fm * 16 + lk * 4)] = pk;
    }
    dsum += __shfl_xor(dsum, 16);
    dsum += __shfl_xor(dsum, 32);
    if (l < 16) denom_s[w * 16 + l] += dsum;

    // transpose vs -> ek_s (ek dead after P1)
    __syncthreads();
    {
        #pragma unroll
        for (int g = 0; g < 4; g++) {
            bf16x4 pv;
            #pragma unroll
            for (int j = 0; j < 4; j++)
                pv[j] = vs_s[swz128(w * 16 + g * 4 + j, l)];
            *(bf16x4*)&ek_s[swz128(l, w * 16 + g * 4)] = pv;
        }
    }
    __syncthreads();

    // P2: O = S@V + Q@KVprev
    bf16x8 as0 = *(const bf16x8*)&s_s[swz128(w * 16 + lm, lk * 8)];
    bf16x8 as1 = *(const bf16x8*)&s_s[swz128(w * 16 + lm, 32 + lk * 8)];
    f32x4 oacc[4] = {};
    #pragma unroll
    for (int fn = 0; fn < 4; fn++) {
        bf16x8 bv0 = *(const bf16x8*)&ek_s[swz128(fn * 16 + lm, lk * 8)];
        bf16x8 bv1 = *(const bf16x8*)&ek_s[swz128(fn * 16 + lm, 32 + lk * 8)];
        bf16x8 bk0 = *(const bf16x8*)&kvT_s[swz128(fn * 16 + lm, lk * 8)];
        bf16x8 bk1 = *(const bf16x8*)&kvT_s[swz128(fn * 16 + lm, 32 + lk * 8)];
        f32x4 z = oacc[fn];
        z = __builtin_amdgcn_mfma_f32_16x16x32_bf16(as0, bv0, z, 0, 0, 0);
        z = __builtin_amdgcn_mfma_f32_16x16x32_bf16(as1, bv1, z, 0, 0, 0);
        z = __builtin_amdgcn_mfma_f32_16x16x32_bf16(bq0, bk0, z, 0, 0, 0);
        z = __builtin_amdgcn_mfma_f32_16x16x32_bf16(bq1, bk1, z, 0, 0, 0);
        oacc[fn] = z;
    }
    #pragma unroll
    for (int r = 0; r < 4; r++) {
        int i = w * 16 + lk * 4 + r;
        float dinv = 1.0f / fmaxf(denom_s[i], 1e-3f);
        #pragma unroll
        for (int fn = 0; fn < 4; fn++)
            ag[(rowbase + i) * DIM + h * DH + fn * 16 + lm] = (__bf16)(oacc[fn][r] * dinv);
    }
}

// ---------------- launch --------------------------------------------------------
extern "C" void kernel_launch(void* const* d_in, const int* in_sizes, int n_in,
                              void* d_out, int out_size, void* d_ws, size_t ws_size,
                              hipStream_t stream) {
    (void)in_sizes; (void)n_in; (void)out_size; (void)ws_size;
    const float* x_in  = (const float*)d_in[0];
    const float* ln1_g = (const float*)d_in[1];
    const float* ln1_b = (const float*)d_in[2];
    const float* Wq    = (const float*)d_in[3];
    const float* Wk    = (const float*)d_in[4];
    const float* Wv    = (const float*)d_in[5];
    const float* Wo    = (const float*)d_in[6];
    const float* bo    = (const float*)d_in[7];
    const float* ln2_g = (const float*)d_in[8];
    const float* ln2_b = (const float*)d_in[9];
    const float* W1    = (const float*)d_in[10];
    const float* b1    = (const float*)d_in[11];
    const float* W2    = (const float*)d_in[12];
    const float* b2    = (const float*)d_in[13];

    float* x = (float*)d_out;
    const size_t MB = 1024 * 1024;
    char* base = (char*)d_ws;

    __bf16* qkv    = (__bf16*)base;
    __bf16* partsO = (__bf16*)base;
    __bf16* h1     = (__bf16*)base;
    __bf16* xn     = (__bf16*)(base + 32 * MB);
    __bf16* parts  = (__bf16*)(base + 32 * MB);
    __bf16* a      = (__bf16*)(base + 40 * MB);
    __bf16* KVT    = (__bf16*)(base + 48 * MB);  // 8MB bf16
    float*  Ks     = (float*)(base + 64 * MB);
    __bf16* wqkt   = (__bf16*)(base + 65 * MB);  // 6MB
    __bf16* wot    = (__bf16*)(base + 71 * MB);  // 2MB
    __bf16* w1t    = (__bf16*)(base + 73 * MB);  // 8MB
    __bf16* w2t    = (__bf16*)(base + 81 * MB);  // 8MB

    dim3 gScan(17, BB * NH);

    for (int l = 0; l < DEPTH; l++) {
        const float* wq = Wq + (size_t)l * DIM * DIM;
        const float* wk = Wk + (size_t)l * DIM * DIM;
        const float* wv = Wv + (size_t)l * DIM * DIM;
        const float* wo = Wo + (size_t)l * DIM * DIM;
        const float* w1 = W1 + (size_t)l * DIM * FFD;
        const float* w2 = W2 + (size_t)l * FFD * DIM;

        transpose_all<<<6144, 256, 0, stream>>>(wq, wk, wv, wo, w1, w2,
                                                wqkt, wot, w1t, w2t);

        // pre-norm attention block
        if (l == 0)
            ln_kernel<<<ROWS, 256, 0, stream>>>(x_in, ln1_g, ln1_b, xn);
        gemm256<0, 1, 3><<<16 * 16, 512, 0, stream>>>(xn, wqkt, qkv, nullptr, nullptr,
                                                      ROWS, QKP, DIM, DIM, 16, 16, 1);
        attn_local_m<<<BB * NH * NCHK, 256, 0, stream>>>(qkv, KVT, Ks);
        attn_scan2<<<gScan, 256, 0, stream>>>(KVT, Ks);
        attn_out_m<<<BB * NH * NCHK, 256, 0, stream>>>(qkv, KVT, Ks, a);
        // O-proj: split-K 4 over K=1024 -> bf16 partials (qkv dead)
        gemm256<0, 1, 4><<<4 * 16 * 4, 512, 0, stream>>>(a, wot, partsO, nullptr, nullptr,
                                                         ROWS, DIM, DIM / 4, DIM, 4, 16, 4);
        // layer 0 reads the residual source directly from x_in (no memcpy)
        reduce4ln<1><<<ROWS, 256, 0, stream>>>(partsO, bo + l * DIM,
                                               l == 0 ? x_in : x, x,
                                               ln2_g + l * DIM, ln2_b + l * DIM, xn);

        // pre-norm FF block (partsO dead -> h1 aliases)
        gemm256<2, 1, 4><<<16 * 16, 512, 0, stream>>>(xn, w1t, h1, b1 + l * FFD, nullptr,
                                                      ROWS, FFD, DIM, DIM, 16, 16, 1);
        gemm256<0, 1, 4><<<4 * 16 * 4, 512, 0, stream>>>(h1, w2t, parts, nullptr, nullptr,
                                                         ROWS, DIM, FFD / 4, FFD, 4, 16, 4);
        if (l + 1 < DEPTH)
            reduce4ln<1><<<ROWS, 256, 0, stream>>>(parts, b2 + l * DIM, x, x,
                                                   ln1_g + (l + 1) * DIM,
                                                   ln1_b + (l + 1) * DIM, xn);
        else
            reduce4ln<0><<<ROWS, 256, 0, stream>>>(parts, b2 + l * DIM, x, x,
                                                   nullptr, nullptr, nullptr);
    }
}